// Round 4
// baseline (1049.640 us; speedup 1.0000x reference)
//
#include <hip/hip_runtime.h>

#define SQLEN 2048
#define QKVW 12288
#define NHEADS 16
#define HEADD 256

typedef unsigned short u16;
typedef __bf16 bf16x8 __attribute__((ext_vector_type(8)));
typedef float f32x4 __attribute__((ext_vector_type(4)));

__device__ __forceinline__ float bf2f(u16 u) {
  union { unsigned int i; float f; } v; v.i = ((unsigned int)u) << 16; return v.f;
}
__device__ __forceinline__ u16 f2bf(float f) {
  union { float f; unsigned int i; } v; v.f = f;
  unsigned int x = v.i;
  return (u16)((x + 0x7fffu + ((x >> 16) & 1u)) >> 16);
}

// async global->LDS, 16B per lane. LDS dest must be wave-uniform base + lane*16.
__device__ __forceinline__ void gl_lds16(const u16* g, u16* l) {
  __builtin_amdgcn_global_load_lds(
      (const __attribute__((address_space(1))) void*)g,
      (__attribute__((address_space(3))) void*)l, 16, 0, 0);
}

// ---------------------------------------------------------------------------
// f32 -> bf16 elementwise convert (8 elems/thread, float4 loads).
// ---------------------------------------------------------------------------
__global__ __launch_bounds__(256) void f32_to_bf16(
    const float* __restrict__ src, u16* __restrict__ dst) {
  long i = (long)(blockIdx.x * 256 + threadIdx.x) * 8;
  float4 a = *reinterpret_cast<const float4*>(src + i);
  float4 b = *reinterpret_cast<const float4*>(src + i + 4);
  u16 tmp[8] = {f2bf(a.x), f2bf(a.y), f2bf(a.z), f2bf(a.w),
                f2bf(b.x), f2bf(b.y), f2bf(b.z), f2bf(b.w)};
  *reinterpret_cast<uint4*>(dst + i) = *reinterpret_cast<uint4*>(tmp);
}

// ---------------------------------------------------------------------------
// 64x64-tiled transpose f32 src -> bf16 dst, XOR-swizzled LDS.
// ---------------------------------------------------------------------------
__global__ __launch_bounds__(256) void ktranspose_f32(
    const float* __restrict__ src, u16* __restrict__ dst,
    int src_ld, int dst_ld) {
  __shared__ __align__(16) u16 t[64][64];
  const int c0 = blockIdx.x * 64, r0 = blockIdx.y * 64;
  const int tid = threadIdx.x;
  #pragma unroll
  for (int it = 0; it < 2; ++it) {
    int c = tid + it * 256;
    int r = c >> 3, ch = c & 7;
    const float* sp = src + (long)(r0 + r) * src_ld + c0 + ch * 8;
    float4 v0 = *reinterpret_cast<const float4*>(sp);
    float4 v1 = *reinterpret_cast<const float4*>(sp + 4);
    u16 tmp[8] = {f2bf(v0.x), f2bf(v0.y), f2bf(v0.z), f2bf(v0.w),
                  f2bf(v1.x), f2bf(v1.y), f2bf(v1.z), f2bf(v1.w)};
    int sw = ch ^ (r & 7);
    *reinterpret_cast<uint4*>(&t[r][sw * 8]) = *reinterpret_cast<uint4*>(tmp);
  }
  __syncthreads();
  #pragma unroll
  for (int it = 0; it < 2; ++it) {
    int c = tid + it * 256;
    int rr = c >> 3, ch = c & 7;
    u16 tmp[8];
    #pragma unroll
    for (int j = 0; j < 8; ++j) {
      int k = ch * 8 + j;
      int sw = (rr >> 3) ^ (k & 7);
      tmp[j] = t[k][sw * 8 + (rr & 7)];
    }
    *reinterpret_cast<uint4*>(dst + (long)(c0 + rr) * dst_ld + r0 + ch * 8) =
        *reinterpret_cast<uint4*>(tmp);
  }
}

// ---------------------------------------------------------------------------
// 64x64-tiled bf16 transpose with batch-z offsets (for V -> V^T per head).
// ---------------------------------------------------------------------------
__global__ __launch_bounds__(256) void ktranspose_bf16(
    const u16* __restrict__ src, u16* __restrict__ dst,
    int src_ld, int dst_ld, long src_off,
    long szs1, long szs2, long dzs1, long dzs2) {
  __shared__ __align__(16) u16 t[64][64];
  const int z = blockIdx.z;
  const u16* s = src + src_off + (long)(z >> 4) * szs1 + (long)(z & 15) * szs2;
  u16* d = dst + (long)(z >> 4) * dzs1 + (long)(z & 15) * dzs2;
  const int c0 = blockIdx.x * 64, r0 = blockIdx.y * 64;
  const int tid = threadIdx.x;
  #pragma unroll
  for (int it = 0; it < 2; ++it) {
    int c = tid + it * 256;
    int r = c >> 3, ch = c & 7;
    uint4 v = *reinterpret_cast<const uint4*>(s + (long)(r0 + r) * src_ld + c0 + ch * 8);
    int sw = ch ^ (r & 7);
    *reinterpret_cast<uint4*>(&t[r][sw * 8]) = v;
  }
  __syncthreads();
  #pragma unroll
  for (int it = 0; it < 2; ++it) {
    int c = tid + it * 256;
    int rr = c >> 3, ch = c & 7;
    u16 tmp[8];
    #pragma unroll
    for (int j = 0; j < 8; ++j) {
      int k = ch * 8 + j;
      int sw = (rr >> 3) ^ (k & 7);
      tmp[j] = t[k][sw * 8 + (rr & 7)];
    }
    *reinterpret_cast<uint4*>(d + (long)(c0 + rr) * dst_ld + r0 + ch * 8) =
        *reinterpret_cast<uint4*>(tmp);
  }
}

// ---------------------------------------------------------------------------
// C = A @ BT^T : 256x256 tile, BK=64, 8 waves, 8-phase schedule, XOR-swizzled
// LDS. Natural blockIdx mapping (XCD remap regressed: FETCH 232->620 MB, R2).
//
// Staging ledger (2 gl_lds rounds per phase, m201 steady-state depth):
//   ph1(t): B2,B3(t+1) ; ph2(t): A0,A2(t+2) ; ph3(t): B0,B1(t+2) ;
//   ph4(t): A1,A3(t+2).  End-of-iter outstanding = 6+2+6 = 14; vmcnt(6)
//   drains all 8 of tile t+1, keeps t+2's 6 in flight.
// grid: (N/256, M/256)
// ---------------------------------------------------------------------------
template <typename OUT_T>
__global__ __launch_bounds__(512, 2) void gemm_bt8(
    const u16* __restrict__ A, const u16* __restrict__ BT, OUT_T* __restrict__ C,
    int M, int N, int K) {
  (void)M;
  __shared__ __align__(16) u16 As[2][256][64];
  __shared__ __align__(16) u16 Bs[2][256][64];
  const int tid = threadIdx.x;
  const int wave = tid >> 6, lane = tid & 63;
  const int quad = lane >> 4, l16 = lane & 15;
  const int wm = (wave >> 2) * 128, wn = (wave & 3) * 64;
  const long m0 = (long)blockIdx.y * 256, n0 = (long)blockIdx.x * 256;
  const int sw = l16 & 7;
  const int ca0 = (quad ^ sw) * 8;
  const int ca1 = ((4 + quad) ^ sw) * 8;
  const int srow = tid >> 3;
  const int sdst8 = (tid & 7) * 8;
  const int ssrc8 = ((tid & 7) ^ (srow & 7)) * 8;
  const long Kl = K;
  const u16* gA = A + (m0 + srow) * Kl + ssrc8;
  const u16* gB = BT + (n0 + srow) * Kl + ssrc8;
  const int nt = K >> 6;

  f32x4 acc[8][4] = {};
  bf16x8 af[4][2];
  bf16x8 bfr[4][2];

#define STAGE_A(BB, R, K0) \
  gl_lds16(gA + (long)((R) << 6) * Kl + (K0), &As[BB][((R) << 6) + srow][sdst8])
#define STAGE_B(BB, R, K0) \
  gl_lds16(gB + (long)((R) << 6) * Kl + (K0), &Bs[BB][((R) << 6) + srow][sdst8])
#define READ_A(BB, RBASE)                                              \
  _Pragma("unroll") for (int i4 = 0; i4 < 4; ++i4) {                   \
    const u16* p_ = &As[BB][(RBASE) + i4 * 16 + l16][0];               \
    af[i4][0] = *reinterpret_cast<const bf16x8*>(p_ + ca0);            \
    af[i4][1] = *reinterpret_cast<const bf16x8*>(p_ + ca1);            \
  }
#define READ_B(BB, JB)                                                 \
  _Pragma("unroll") for (int j2 = 0; j2 < 2; ++j2) {                   \
    const u16* p_ = &Bs[BB][wn + ((JB) + j2) * 16 + l16][0];           \
    bfr[(JB) + j2][0] = *reinterpret_cast<const bf16x8*>(p_ + ca0);    \
    bfr[(JB) + j2][1] = *reinterpret_cast<const bf16x8*>(p_ + ca1);    \
  }
#define QUADMFMA(MB, NB)                                               \
  _Pragma("unroll") for (int i4 = 0; i4 < 4; ++i4)                     \
  _Pragma("unroll") for (int j2 = 0; j2 < 2; ++j2)                     \
  _Pragma("unroll") for (int s = 0; s < 2; ++s)                        \
    acc[(MB) + i4][(NB) + j2] = __builtin_amdgcn_mfma_f32_16x16x32_bf16( \
        af[i4][s], bfr[(NB) + j2][s], acc[(MB) + i4][(NB) + j2], 0, 0, 0);
#define BAR() asm volatile("s_barrier" ::: "memory")
#define LGKM0() asm volatile("s_waitcnt lgkmcnt(0)" ::: "memory")

  // prologue: tile0 full (8 rounds) -> buf0; tile1 partial (6 rounds) -> buf1
  STAGE_A(0, 0, 0); STAGE_A(0, 1, 0); STAGE_A(0, 2, 0); STAGE_A(0, 3, 0);
  STAGE_B(0, 0, 0); STAGE_B(0, 1, 0); STAGE_B(0, 2, 0); STAGE_B(0, 3, 0);
  if (nt > 1) {
    STAGE_A(1, 0, 64); STAGE_A(1, 2, 64);
    STAGE_B(1, 0, 64); STAGE_B(1, 1, 64);
    STAGE_A(1, 1, 64); STAGE_A(1, 3, 64);
    asm volatile("s_waitcnt vmcnt(6)" ::: "memory");
  } else {
    asm volatile("s_waitcnt vmcnt(0)" ::: "memory");
  }
  BAR();

  for (int t = 0; t < nt; ++t) {
    const int b = t & 1;
    const long kn = (long)(t + 1) << 6;
    const long kn2 = (long)(t + 2) << 6;
    const bool st1 = (t + 1 < nt), st2 = (t + 2 < nt);
    // ---- phase 1: reads A(wm)+B0 (12 ds); stage B2,B3(t+1); MFMA Q(0,0)
    READ_A(b, wm);
    READ_B(b, 0);
    if (st1) { STAGE_B(b ^ 1, 2, kn); STAGE_B(b ^ 1, 3, kn); }
    asm volatile("s_waitcnt lgkmcnt(8)" ::: "memory");
    BAR(); LGKM0();
    __builtin_amdgcn_s_setprio(1);
    QUADMFMA(0, 0);
    __builtin_amdgcn_s_setprio(0);
    BAR();
    // ---- phase 2: reads B2 (4 ds); stage A0,A2(t+2); MFMA Q(0,1)
    READ_B(b, 2);
    if (st2) { STAGE_A(b, 0, kn2); STAGE_A(b, 2, kn2); }
    BAR(); LGKM0();
    __builtin_amdgcn_s_setprio(1);
    QUADMFMA(0, 2);
    __builtin_amdgcn_s_setprio(0);
    BAR();
    // ---- phase 3: reads A(wm+64) (8 ds); stage B0,B1(t+2); MFMA Q(1,1)
    READ_A(b, wm + 64);
    if (st2) { STAGE_B(b, 0, kn2); STAGE_B(b, 1, kn2); }
    BAR(); LGKM0();
    __builtin_amdgcn_s_setprio(1);
    QUADMFMA(4, 2);
    __builtin_amdgcn_s_setprio(0);
    BAR();
    // ---- phase 4: no ds reads; stage A1,A3(t+2); MFMA Q(1,0)
    if (st2) { STAGE_A(b, 1, kn2); STAGE_A(b, 3, kn2); }
    BAR();
    __builtin_amdgcn_s_setprio(1);
    QUADMFMA(4, 0);
    __builtin_amdgcn_s_setprio(0);
    if (st2)      asm volatile("s_waitcnt vmcnt(6)" ::: "memory");
    else if (st1) asm volatile("s_waitcnt vmcnt(0)" ::: "memory");
    BAR();
  }

  #pragma unroll
  for (int i = 0; i < 8; ++i)
    #pragma unroll
    for (int j = 0; j < 4; ++j) {
      long col = n0 + wn + j * 16 + l16;
      #pragma unroll
      for (int r = 0; r < 4; ++r) {
        long row = m0 + wm + i * 16 + quad * 4 + r;
        if constexpr (sizeof(OUT_T) == 4)
          C[row * (long)N + col] = acc[i][j][r];
        else
          C[row * (long)N + col] = f2bf(acc[i][j][r]);
      }
    }
#undef STAGE_A
#undef STAGE_B
#undef READ_A
#undef READ_B
#undef QUADMFMA
#undef BAR
#undef LGKM0
}

// ---------------------------------------------------------------------------
// RoPE trig table: tab[pos*128+i] = (cos, sin)(pos * theta^(-i/128)).
// ---------------------------------------------------------------------------
__global__ __launch_bounds__(256) void rope_table(float2* __restrict__ tab) {
  int idx = blockIdx.x * 256 + threadIdx.x;
  int pos = idx >> 7, i = idx & 127;
  float inv_freq = exp2f((float)i * (-13.287712379549449f / 128.0f));
  float ang = (float)pos * inv_freq;
  float sv, cv;
  sincosf(ang, &sv, &cv);
  tab[idx] = make_float2(cv, sv);
}

// ---------------------------------------------------------------------------
// NeoX RoPE in-place on q,k parts of qkv[4096][12288] (bf16), table-driven.
// ---------------------------------------------------------------------------
__global__ __launch_bounds__(256) void rope_kernel(
    u16* __restrict__ qkv, const int* __restrict__ positions,
    const float2* __restrict__ tab) {
  int idx = blockIdx.x * 256 + threadIdx.x;
  int i = idx & 127;
  int head = (idx >> 7) & 31;
  int row = idx >> 12;
  int col = (head < NHEADS) ? head * HEADD : 4096 + (head - NHEADS) * HEADD;
  u16* p = qkv + (long)row * QKVW + col;
  float x1 = bf2f(p[i]), x2 = bf2f(p[i + 128]);
  float2 cssn = tab[positions[row] * 128 + i];
  p[i] = f2bf(x1 * cssn.x - x2 * cssn.y);
  p[i + 128] = f2bf(x2 * cssn.x + x1 * cssn.y);
}

// ---------------------------------------------------------------------------
// Flash attention, causal, load-balanced persistent blocks.
// Double-buffered K/V staged via global_load_lds (inverse-swizzled source +
// XOR-swizzled ds_read), full-iteration prefetch (vmcnt(16) across seams),
// Q-frags direct from global, setprio around MFMA, defer-max (T13, THR=8).
// Block (p,bh) processes q-tiles 31-p then p (33 K-iters) -> flat makespan.
// grid: (16, B*NH), 256 threads.
// ---------------------------------------------------------------------------
__global__ __launch_bounds__(256, 1) void attn_kernel(
    const u16* __restrict__ qkv, const u16* __restrict__ VT,
    u16* __restrict__ attnout) {
  const int p = blockIdx.x;
  const int bh = blockIdx.y;
  const int b = bh >> 4, h = bh & 15;
  const int tid = threadIdx.x;
  const int wave = tid >> 6, lane = tid & 63;
  const int quad = lane >> 4, l16 = lane & 15;
  const int sw7 = l16 & 7;

  __shared__ __align__(16) u16 Ks[2][64][256];  // K tiles, XOR-swizzled
  __shared__ __align__(16) u16 Vs[2][256][64];  // V^T tiles, XOR-swizzled
  __shared__ __align__(16) u16 Ps[64][72];      // P relayout (wave-private rows)

  const u16* qp = qkv + (long)b * SQLEN * QKVW + h * HEADD;
  const u16* kp = qp + 4096;
  const u16* vtp = VT + (long)bh * HEADD * SQLEN;
  const float cs = 0.0625f * 1.4426950408889634f;  // scale * log2(e)

  // staging bases: LDS[r][c] = G[r][c ^ (r&7)] (16B-chunk XOR involution)
  const u16* ksrc = kp + (long)(tid >> 5) * QKVW + ((tid & 31) ^ ((tid >> 5) & 7)) * 8;
  const u16* vsrc = vtp + (long)(tid >> 3) * SQLEN + ((tid & 7) ^ ((tid >> 3) & 7)) * 8;
  u16* kdst = &Ks[0][0][0] + tid * 8;
  u16* vdst = &Vs[0][0][0] + tid * 8;

#define STAGE_K(KT, BB) { const u16* gk_ = ksrc + (long)(KT) * 64 * QKVW;      \
  _Pragma("unroll") for (int it = 0; it < 8; ++it)                             \
    gl_lds16(gk_ + (long)it * 8 * QKVW, kdst + (BB) * 16384 + it * 2048); }
#define STAGE_V(KT, BB) { const u16* gv_ = vsrc + (KT) * 64;                   \
  _Pragma("unroll") for (int it = 0; it < 8; ++it)                             \
    gl_lds16(gv_ + (long)it * 32 * SQLEN, vdst + (BB) * 16384 + it * 2048); }
#define ABAR() asm volatile("s_barrier" ::: "memory")

  for (int half = 0; half < 2; ++half) {
    const int qt = half ? p : 31 - p;  // heavy tile first

    ABAR();  // prev half's LDS readers done before restaging
    const u16* qrow = qp + (long)(qt * 64 + wave * 16 + l16) * QKVW + quad * 8;
    bf16x8 qf[8];
    #pragma unroll
    for (int s = 0; s < 8; ++s)
      qf[s] = *reinterpret_cast<const bf16x8*>(qrow + s * 32);

    STAGE_K(0, 0); STAGE_V(0, 0);
    if (qt > 0) {
      STAGE_K(1, 1); STAGE_V(1, 1);
      asm volatile("s_waitcnt vmcnt(16)" ::: "memory");
    } else {
      asm volatile("s_waitcnt vmcnt(0)" ::: "memory");
    }
    ABAR();

    float m_i[4], l_i[4];
    #pragma unroll
    for (int r = 0; r < 4; ++r) { m_i[r] = -INFINITY; l_i[r] = 0.f; }
    f32x4 o[16] = {};

    for (int kt = 0; kt <= qt; ++kt) {
      const int bb = kt & 1;
      // ---- QK^T (reads Ks[bb])
      f32x4 sc[4] = {};
      __builtin_amdgcn_s_setprio(1);
      #pragma unroll
      for (int s = 0; s < 8; ++s) {
        #pragma unroll
        for (int nb = 0; nb < 4; ++nb) {
          bf16x8 kf = *reinterpret_cast<const bf16x8*>(
              &Ks[bb][nb * 16 + l16][(((s << 2) + quad) ^ sw7) * 8]);
          sc[nb] = __builtin_amdgcn_mfma_f32_16x16x32_bf16(qf[s], kf, sc[nb], 0, 0, 0);
        }
      }
      __builtin_amdgcn_s_setprio(0);
      // ---- mask + online softmax with defer-max
      const bool diag = (kt == qt);
      #pragma unroll
      for (int nb = 0; nb < 4; ++nb)
        #pragma unroll
        for (int r = 0; r < 4; ++r) {
          float v = sc[nb][r] * cs;
          if (diag) {
            int colL = nb * 16 + l16, rowL = wave * 16 + quad * 4 + r;
            if (colL > rowL) v = -INFINITY;
          }
          sc[nb][r] = v;
        }
      float t4[4];
      bool need = false;
      #pragma unroll
      for (int r = 0; r < 4; ++r) {
        float t = fmaxf(fmaxf(sc[0][r], sc[1][r]), fmaxf(sc[2][r], sc[3][r]));
        #pragma unroll
        for (int d = 1; d < 16; d <<= 1) t = fmaxf(t, __shfl_xor(t, d));
        t4[r] = t;
        need = need || (t > m_i[r] + 8.0f);
      }
      if (__any(need)) {
        float alpha[4];
        #pragma unroll
        for (int r = 0; r < 4; ++r) {
          float mn = fmaxf(m_i[r], t4[r]);
          alpha[r] = exp2f(m_i[r] - mn);
          m_i[r] = mn;
          l_i[r] *= alpha[r];
        }
        #pragma unroll
        for (int c16 = 0; c16 < 16; ++c16)
          #pragma unroll
          for (int r = 0; r < 4; ++r)
            o[c16][r] *= alpha[r];
      }
      #pragma unroll
      for (int r = 0; r < 4; ++r) {
        float t = 0.f;
        #pragma unroll
        for (int nb = 0; nb < 4; ++nb) {
          float pr = exp2f(sc[nb][r] - m_i[r]);
          sc[nb][r] = pr;
          t += pr;
        }
        #pragma unroll
        for (int d = 1; d < 16; d <<= 1) t += __shfl_xor(t, d);
        l_i[r] += t;
      }
      ABAR();  // all waves done reading Ks[bb]
      if (kt + 2 <= qt) STAGE_K(kt + 2, bb);
      // ---- P relayout (wave-private rows)
      #pragma unroll
      for (int nb = 0; nb < 4; ++nb)
        #pragma unroll
        for (int r = 0; r < 4; ++r)
          Ps[wave * 16 + quad * 4 + r][nb * 16 + l16] = f2bf(sc[nb][r]);
      bf16x8 pf[2];
      #pragma unroll
      for (int s2 = 0; s2 < 2; ++s2)
        pf[s2] = *reinterpret_cast<const bf16x8*>(&Ps[wave * 16 + l16][s2 * 32 + quad * 8]);
      // ---- PV (reads Vs[bb])
      __builtin_amdgcn_s_setprio(1);
      #pragma unroll
      for (int c16 = 0; c16 < 16; ++c16) {
        #pragma unroll
        for (int s2 = 0; s2 < 2; ++s2) {
          bf16x8 vf = *reinterpret_cast<const bf16x8*>(
              &Vs[bb][c16 * 16 + l16][(((s2 << 2) + quad) ^ sw7) * 8]);
          o[c16] = __builtin_amdgcn_mfma_f32_16x16x32_bf16(pf[s2], vf, o[c16], 0, 0, 0);
        }
      }
      __builtin_amdgcn_s_setprio(0);
      if (kt < qt) {
        ABAR();  // all waves done reading Vs[bb]
        if (kt + 2 <= qt) {
          STAGE_V(kt + 2, bb);
          asm volatile("s_waitcnt vmcnt(16)" ::: "memory");
        } else {
          asm volatile("s_waitcnt vmcnt(0)" ::: "memory");
        }
        ABAR();  // tile kt+1 visible to all waves
      }
    }
    // ---- epilogue
    #pragma unroll
    for (int r = 0; r < 4; ++r) {
      float inv = 1.0f / l_i[r];
      long q = qt * 64 + wave * 16 + quad * 4 + r;
      long rowoff = ((long)b * SQLEN + q) * 4096 + h * HEADD;
      #pragma unroll
      for (int c16 = 0; c16 < 16; ++c16)
        attnout[rowoff + c16 * 16 + l16] = f2bf(o[c16][r] * inv);
    }
  }
#undef STAGE_K
#undef STAGE_V
#undef ABAR
}

// ---------------------------------------------------------------------------
extern "C" void kernel_launch(void* const* d_in, const int* in_sizes, int n_in,
                              void* d_out, int out_size, void* d_ws, size_t ws_size,
                              hipStream_t stream) {
  const float* hidden = (const float*)d_in[0];
  const int* positions = (const int*)d_in[1];
  const float* Wqkv = (const float*)d_in[2];
  const float* Wo = (const float*)d_in[3];
  float* out = (float*)d_out;
  char* ws = (char*)d_ws;

  // workspace layout (bytes), total 200 MiB:
  //   [0, 100663296)           qkv   4096x12288 bf16
  //   [100663296, 176160768)   WqkvT 12288x3072 bf16 (dead after GEMM1):
  //     [100663296, 134217728)   attn 4096x4096 bf16
  //     [134217728, 159383552)   WoT  3072x4096 bf16
  //   [176160768, 201326592)   hiddenB 4096x3072 bf16 (dead after GEMM1)
  //   [201326592, 203423744)   rope cos/sin table 2048x128 float2
  //                            (inside VT's slot, but VT is written AFTER
  //                             rope_kernel has consumed the table)
  //   [176160768, 209715200)   VT 32x256x2048 bf16 (written after rope)
  u16* qkv     = (u16*)(ws);
  u16* WqkvT   = (u16*)(ws + 100663296L);
  u16* attn    = (u16*)(ws + 100663296L);
  u16* WoT     = (u16*)(ws + 134217728L);
  u16* hiddenB = (u16*)(ws + 176160768L);
  u16* VT      = (u16*)(ws + 176160768L);
  float2* rtab = (float2*)(ws + 201326592L);

  f32_to_bf16<<<dim3(6144, 1, 1), 256, 0, stream>>>(hidden, hiddenB);
  rope_table<<<dim3(1024, 1, 1), 256, 0, stream>>>(rtab);
  ktranspose_f32<<<dim3(192, 48, 1), 256, 0, stream>>>(Wqkv, WqkvT, 12288, 3072);
  gemm_bt8<u16><<<dim3(48, 16, 1), 512, 0, stream>>>(
      hiddenB, WqkvT, qkv, 4096, 12288, 3072);
  rope_kernel<<<dim3(65536, 1, 1), 256, 0, stream>>>(qkv, positions, rtab);
  ktranspose_bf16<<<dim3(4, 32, 32), 256, 0, stream>>>(
      qkv, VT, 12288, 2048, 8192,
      25165824L, 256L, 8388608L, 524288L);
  attn_kernel<<<dim3(16, 32, 1), 256, 0, stream>>>(qkv, VT, attn);
  ktranspose_f32<<<dim3(48, 64, 1), 256, 0, stream>>>(Wo, WoT, 3072, 4096);
  gemm_bt8<float><<<dim3(12, 16, 1), 512, 0, stream>>>(
      attn, WoT, out, 4096, 3072, 4096);
}

// Round 5
// 969.519 us; speedup vs baseline: 1.0826x; 1.0826x over previous
//
#include <hip/hip_runtime.h>

#define SQLEN 2048
#define QKVW 12288
#define NHEADS 16
#define HEADD 256

typedef unsigned short u16;
typedef __bf16 bf16x8 __attribute__((ext_vector_type(8)));
typedef float f32x4 __attribute__((ext_vector_type(4)));

__device__ __forceinline__ float bf2f(u16 u) {
  union { unsigned int i; float f; } v; v.i = ((unsigned int)u) << 16; return v.f;
}
__device__ __forceinline__ u16 f2bf(float f) {
  union { float f; unsigned int i; } v; v.f = f;
  unsigned int x = v.i;
  return (u16)((x + 0x7fffu + ((x >> 16) & 1u)) >> 16);
}

// async global->LDS, 16B per lane. LDS dest must be wave-uniform base + lane*16.
__device__ __forceinline__ void gl_lds16(const u16* g, u16* l) {
  __builtin_amdgcn_global_load_lds(
      (const __attribute__((address_space(1))) void*)g,
      (__attribute__((address_space(3))) void*)l, 16, 0, 0);
}

// ---------------------------------------------------------------------------
// f32 -> bf16 elementwise convert (8 elems/thread, float4 loads).
// ---------------------------------------------------------------------------
__global__ __launch_bounds__(256) void f32_to_bf16(
    const float* __restrict__ src, u16* __restrict__ dst) {
  long i = (long)(blockIdx.x * 256 + threadIdx.x) * 8;
  float4 a = *reinterpret_cast<const float4*>(src + i);
  float4 b = *reinterpret_cast<const float4*>(src + i + 4);
  u16 tmp[8] = {f2bf(a.x), f2bf(a.y), f2bf(a.z), f2bf(a.w),
                f2bf(b.x), f2bf(b.y), f2bf(b.z), f2bf(b.w)};
  *reinterpret_cast<uint4*>(dst + i) = *reinterpret_cast<uint4*>(tmp);
}

// ---------------------------------------------------------------------------
// 64x64-tiled transpose f32 src -> bf16 dst, XOR-swizzled LDS.
// ---------------------------------------------------------------------------
__global__ __launch_bounds__(256) void ktranspose_f32(
    const float* __restrict__ src, u16* __restrict__ dst,
    int src_ld, int dst_ld) {
  __shared__ __align__(16) u16 t[64][64];
  const int c0 = blockIdx.x * 64, r0 = blockIdx.y * 64;
  const int tid = threadIdx.x;
  #pragma unroll
  for (int it = 0; it < 2; ++it) {
    int c = tid + it * 256;
    int r = c >> 3, ch = c & 7;
    const float* sp = src + (long)(r0 + r) * src_ld + c0 + ch * 8;
    float4 v0 = *reinterpret_cast<const float4*>(sp);
    float4 v1 = *reinterpret_cast<const float4*>(sp + 4);
    u16 tmp[8] = {f2bf(v0.x), f2bf(v0.y), f2bf(v0.z), f2bf(v0.w),
                  f2bf(v1.x), f2bf(v1.y), f2bf(v1.z), f2bf(v1.w)};
    int sw = ch ^ (r & 7);
    *reinterpret_cast<uint4*>(&t[r][sw * 8]) = *reinterpret_cast<uint4*>(tmp);
  }
  __syncthreads();
  #pragma unroll
  for (int it = 0; it < 2; ++it) {
    int c = tid + it * 256;
    int rr = c >> 3, ch = c & 7;
    u16 tmp[8];
    #pragma unroll
    for (int j = 0; j < 8; ++j) {
      int k = ch * 8 + j;
      int sw = (rr >> 3) ^ (k & 7);
      tmp[j] = t[k][sw * 8 + (rr & 7)];
    }
    *reinterpret_cast<uint4*>(dst + (long)(c0 + rr) * dst_ld + r0 + ch * 8) =
        *reinterpret_cast<uint4*>(tmp);
  }
}

// ---------------------------------------------------------------------------
// 64x64-tiled bf16 transpose with batch-z offsets (for V -> V^T per head).
// ---------------------------------------------------------------------------
__global__ __launch_bounds__(256) void ktranspose_bf16(
    const u16* __restrict__ src, u16* __restrict__ dst,
    int src_ld, int dst_ld, long src_off,
    long szs1, long szs2, long dzs1, long dzs2) {
  __shared__ __align__(16) u16 t[64][64];
  const int z = blockIdx.z;
  const u16* s = src + src_off + (long)(z >> 4) * szs1 + (long)(z & 15) * szs2;
  u16* d = dst + (long)(z >> 4) * dzs1 + (long)(z & 15) * dzs2;
  const int c0 = blockIdx.x * 64, r0 = blockIdx.y * 64;
  const int tid = threadIdx.x;
  #pragma unroll
  for (int it = 0; it < 2; ++it) {
    int c = tid + it * 256;
    int r = c >> 3, ch = c & 7;
    uint4 v = *reinterpret_cast<const uint4*>(s + (long)(r0 + r) * src_ld + c0 + ch * 8);
    int sw = ch ^ (r & 7);
    *reinterpret_cast<uint4*>(&t[r][sw * 8]) = v;
  }
  __syncthreads();
  #pragma unroll
  for (int it = 0; it < 2; ++it) {
    int c = tid + it * 256;
    int rr = c >> 3, ch = c & 7;
    u16 tmp[8];
    #pragma unroll
    for (int j = 0; j < 8; ++j) {
      int k = ch * 8 + j;
      int sw = (rr >> 3) ^ (k & 7);
      tmp[j] = t[k][sw * 8 + (rr & 7)];
    }
    *reinterpret_cast<uint4*>(d + (long)(c0 + rr) * dst_ld + r0 + ch * 8) =
        *reinterpret_cast<uint4*>(tmp);
  }
}

// ---------------------------------------------------------------------------
// C = A @ BT^T : 256x256 tile, BK=64, 8 waves, 8-phase schedule, XOR-swizzled
// LDS.  R1 ledger (proven 308 us / FETCH 232 MB; the deeper vmcnt(6) ledger
// regressed to 342 us / 341 MB in R4 -- wider live window hurts L2/L3 reuse):
//   prologue: tile0 full + A0,A1(t1);  ph1(t): A2,A3(t+1); ph2(t): B0,B1(t+1);
//   ph3(t): B2,B3(t+1); ph4(t): A0,A1(t+2), vmcnt(2).
// ROPE=true: NeoX rope fused into epilogue for col-tiles < 8192 (q,k).
//   Pair (col, col+128) lives at IDENTICAL (i,j,lane,r) coords in wave^2
//   (wn 0<->2, 1<->3): exchange acc as bf16 via flat conflict-free LDS copy,
//   then out = own*c +/- partner*s with cos/sin from the 2 MB L2-hot table.
// grid: (N/256, M/256)
// ---------------------------------------------------------------------------
template <typename OUT_T, bool ROPE>
__global__ __launch_bounds__(512, 2) void gemm_bt8(
    const u16* __restrict__ A, const u16* __restrict__ BT, OUT_T* __restrict__ C,
    int M, int N, int K,
    const float2* __restrict__ rtab, const int* __restrict__ positions) {
  (void)M;
  __shared__ __align__(16) u16 As[2][256][64];
  __shared__ __align__(16) u16 Bs[2][256][64];
  const int tid = threadIdx.x;
  const int wave = tid >> 6, lane = tid & 63;
  const int quad = lane >> 4, l16 = lane & 15;
  const int wm = (wave >> 2) * 128, wn = (wave & 3) * 64;
  const long m0 = (long)blockIdx.y * 256, n0 = (long)blockIdx.x * 256;
  const int sw = l16 & 7;
  const int ca0 = (quad ^ sw) * 8;
  const int ca1 = ((4 + quad) ^ sw) * 8;
  const int srow = tid >> 3;
  const int sdst8 = (tid & 7) * 8;
  const int ssrc8 = ((tid & 7) ^ (srow & 7)) * 8;
  const long Kl = K;
  const u16* gA = A + (m0 + srow) * Kl + ssrc8;
  const u16* gB = BT + (n0 + srow) * Kl + ssrc8;
  const int nt = K >> 6;

  f32x4 acc[8][4] = {};
  bf16x8 af[4][2];
  bf16x8 bfr[4][2];

#define STAGE_A(BB, R, K0) \
  gl_lds16(gA + (long)((R) << 6) * Kl + (K0), &As[BB][((R) << 6) + srow][sdst8])
#define STAGE_B(BB, R, K0) \
  gl_lds16(gB + (long)((R) << 6) * Kl + (K0), &Bs[BB][((R) << 6) + srow][sdst8])
#define READ_A(BB, RBASE)                                              \
  _Pragma("unroll") for (int i4 = 0; i4 < 4; ++i4) {                   \
    const u16* p_ = &As[BB][(RBASE) + i4 * 16 + l16][0];               \
    af[i4][0] = *reinterpret_cast<const bf16x8*>(p_ + ca0);            \
    af[i4][1] = *reinterpret_cast<const bf16x8*>(p_ + ca1);            \
  }
#define READ_B(BB, JB)                                                 \
  _Pragma("unroll") for (int j2 = 0; j2 < 2; ++j2) {                   \
    const u16* p_ = &Bs[BB][wn + ((JB) + j2) * 16 + l16][0];           \
    bfr[(JB) + j2][0] = *reinterpret_cast<const bf16x8*>(p_ + ca0);    \
    bfr[(JB) + j2][1] = *reinterpret_cast<const bf16x8*>(p_ + ca1);    \
  }
#define QUADMFMA(MB, NB)                                               \
  _Pragma("unroll") for (int i4 = 0; i4 < 4; ++i4)                     \
  _Pragma("unroll") for (int j2 = 0; j2 < 2; ++j2)                     \
  _Pragma("unroll") for (int s = 0; s < 2; ++s)                        \
    acc[(MB) + i4][(NB) + j2] = __builtin_amdgcn_mfma_f32_16x16x32_bf16( \
        af[i4][s], bfr[(NB) + j2][s], acc[(MB) + i4][(NB) + j2], 0, 0, 0);
#define BAR() asm volatile("s_barrier" ::: "memory")
#define LGKM0() asm volatile("s_waitcnt lgkmcnt(0)" ::: "memory")

  // prologue: tile0 full (8 rounds) -> buf0; tile1 rounds A0,A1 -> buf1
  STAGE_A(0, 0, 0); STAGE_A(0, 1, 0); STAGE_A(0, 2, 0); STAGE_A(0, 3, 0);
  STAGE_B(0, 0, 0); STAGE_B(0, 1, 0); STAGE_B(0, 2, 0); STAGE_B(0, 3, 0);
  if (nt > 1) {
    STAGE_A(1, 0, 64); STAGE_A(1, 1, 64);
    asm volatile("s_waitcnt vmcnt(2)" ::: "memory");
  } else {
    asm volatile("s_waitcnt vmcnt(0)" ::: "memory");
  }
  BAR();

  for (int t = 0; t < nt; ++t) {
    const int b = t & 1;
    const long kn = (long)(t + 1) << 6;
    const long kn2 = (long)(t + 2) << 6;
    const bool st1 = (t + 1 < nt), st2 = (t + 2 < nt);
    // ---- phase 1: reads A(wm)+B0 (12 ds); stage A2,A3(t+1); MFMA Q(0,0)
    READ_A(b, wm);
    READ_B(b, 0);
    if (st1) { STAGE_A(b ^ 1, 2, kn); STAGE_A(b ^ 1, 3, kn); }
    BAR(); LGKM0();
    __builtin_amdgcn_s_setprio(1);
    QUADMFMA(0, 0);
    __builtin_amdgcn_s_setprio(0);
    BAR();
    // ---- phase 2: reads B2 (4 ds); stage B0,B1(t+1); MFMA Q(0,1)
    READ_B(b, 2);
    if (st1) { STAGE_B(b ^ 1, 0, kn); STAGE_B(b ^ 1, 1, kn); }
    BAR(); LGKM0();
    __builtin_amdgcn_s_setprio(1);
    QUADMFMA(0, 2);
    __builtin_amdgcn_s_setprio(0);
    BAR();
    // ---- phase 3: reads A(wm+64) (8 ds); stage B2,B3(t+1); MFMA Q(1,1)
    READ_A(b, wm + 64);
    if (st1) { STAGE_B(b ^ 1, 2, kn); STAGE_B(b ^ 1, 3, kn); }
    BAR(); LGKM0();
    __builtin_amdgcn_s_setprio(1);
    QUADMFMA(4, 2);
    __builtin_amdgcn_s_setprio(0);
    BAR();
    // ---- phase 4: no ds reads; stage A0,A1(t+2) into buf b; MFMA Q(1,0)
    if (st2) { STAGE_A(b, 0, kn2); STAGE_A(b, 1, kn2); }
    BAR();
    __builtin_amdgcn_s_setprio(1);
    QUADMFMA(4, 0);
    __builtin_amdgcn_s_setprio(0);
    if (st2)      asm volatile("s_waitcnt vmcnt(2)" ::: "memory");
    else if (st1) asm volatile("s_waitcnt vmcnt(0)" ::: "memory");
    BAR();
  }

  if constexpr (ROPE) {
    if (n0 < 8192) {
      // ---- fused NeoX rope epilogue (q,k col-tiles) ----
      // exchange bf16 acc with partner wave (wave^2) via flat LDS regions
      u16* xbase = (wave < 4) ? &As[0][0][0] : &Bs[0][0][0];
      const int w3 = wave & 3;
      u16* xw = xbase + w3 * 8192;               // 16 KB region (u16 units)
      const u16* xr = xbase + (w3 ^ 2) * 8192;
      #pragma unroll
      for (int i = 0; i < 8; ++i)
        #pragma unroll
        for (int j = 0; j < 4; ++j) {
          u16 pk[4] = {f2bf(acc[i][j][0]), f2bf(acc[i][j][1]),
                       f2bf(acc[i][j][2]), f2bf(acc[i][j][3])};
          *reinterpret_cast<uint2*>(xw + (i * 4 + j) * 256 + lane * 4) =
              *reinterpret_cast<uint2*>(pk);
        }
      __syncthreads();
      const float sgn = (wn < 128) ? -1.f : 1.f;   // x1 side: -s, x2 side: +s
      const int fi = (wn & 64) + l16;              // + j*16 below
      #pragma unroll
      for (int i = 0; i < 8; ++i) {
        int pos4[4];
        #pragma unroll
        for (int r = 0; r < 4; ++r)
          pos4[r] = positions[m0 + wm + i * 16 + quad * 4 + r];
        #pragma unroll
        for (int j = 0; j < 4; ++j) {
          u16 pb[4];
          *reinterpret_cast<uint2*>(pb) =
              *reinterpret_cast<const uint2*>(xr + (i * 4 + j) * 256 + lane * 4);
          long col = n0 + wn + j * 16 + l16;
          #pragma unroll
          for (int r = 0; r < 4; ++r) {
            float2 e = rtab[(long)pos4[r] * 128 + fi + j * 16];
            float outv = acc[i][j][r] * e.x + sgn * bf2f(pb[r]) * e.y;
            long row = m0 + wm + i * 16 + quad * 4 + r;
            C[row * (long)N + col] = (OUT_T)f2bf(outv);
          }
        }
      }
      return;
    }
  }
  // ---- plain epilogue ----
  #pragma unroll
  for (int i = 0; i < 8; ++i)
    #pragma unroll
    for (int j = 0; j < 4; ++j) {
      long col = n0 + wn + j * 16 + l16;
      #pragma unroll
      for (int r = 0; r < 4; ++r) {
        long row = m0 + wm + i * 16 + quad * 4 + r;
        if constexpr (sizeof(OUT_T) == 4)
          C[row * (long)N + col] = acc[i][j][r];
        else
          C[row * (long)N + col] = f2bf(acc[i][j][r]);
      }
    }
#undef STAGE_A
#undef STAGE_B
#undef READ_A
#undef READ_B
#undef QUADMFMA
#undef BAR
#undef LGKM0
}

// ---------------------------------------------------------------------------
// RoPE trig table: tab[pos*128+i] = (cos, sin)(pos * theta^(-i/128)).
// ---------------------------------------------------------------------------
__global__ __launch_bounds__(256) void rope_table(float2* __restrict__ tab) {
  int idx = blockIdx.x * 256 + threadIdx.x;
  int pos = idx >> 7, i = idx & 127;
  float inv_freq = exp2f((float)i * (-13.287712379549449f / 128.0f));
  float ang = (float)pos * inv_freq;
  float sv, cv;
  sincosf(ang, &sv, &cv);
  tab[idx] = make_float2(cv, sv);
}

// ---------------------------------------------------------------------------
// Flash attention, causal, load-balanced persistent blocks.
// Double-buffered K/V staged via global_load_lds (inverse-swizzled source +
// XOR-swizzled ds_read), full-iteration prefetch (vmcnt(16) across seams),
// Q-frags direct from global, setprio around MFMA. (defer-max dropped: R4
// regressed ~40us, suspected VGPR-pressure from o[] live across the branch.)
// Block (p,bh) processes q-tiles 31-p then p (33 K-iters) -> flat makespan.
// grid: (16, B*NH), 256 threads.
// ---------------------------------------------------------------------------
__global__ __launch_bounds__(256, 1) void attn_kernel(
    const u16* __restrict__ qkv, const u16* __restrict__ VT,
    u16* __restrict__ attnout) {
  const int p = blockIdx.x;
  const int bh = blockIdx.y;
  const int b = bh >> 4, h = bh & 15;
  const int tid = threadIdx.x;
  const int wave = tid >> 6, lane = tid & 63;
  const int quad = lane >> 4, l16 = lane & 15;
  const int sw7 = l16 & 7;

  __shared__ __align__(16) u16 Ks[2][64][256];  // K tiles, XOR-swizzled
  __shared__ __align__(16) u16 Vs[2][256][64];  // V^T tiles, XOR-swizzled
  __shared__ __align__(16) u16 Ps[64][72];      // P relayout (wave-private rows)

  const u16* qp = qkv + (long)b * SQLEN * QKVW + h * HEADD;
  const u16* kp = qp + 4096;
  const u16* vtp = VT + (long)bh * HEADD * SQLEN;
  const float cs = 0.0625f * 1.4426950408889634f;  // scale * log2(e)

  // staging bases: LDS[r][c] = G[r][c ^ (r&7)] (16B-chunk XOR involution)
  const u16* ksrc = kp + (long)(tid >> 5) * QKVW + ((tid & 31) ^ ((tid >> 5) & 7)) * 8;
  const u16* vsrc = vtp + (long)(tid >> 3) * SQLEN + ((tid & 7) ^ ((tid >> 3) & 7)) * 8;
  u16* kdst = &Ks[0][0][0] + tid * 8;
  u16* vdst = &Vs[0][0][0] + tid * 8;

#define STAGE_K(KT, BB) { const u16* gk_ = ksrc + (long)(KT) * 64 * QKVW;      \
  _Pragma("unroll") for (int it = 0; it < 8; ++it)                             \
    gl_lds16(gk_ + (long)it * 8 * QKVW, kdst + (BB) * 16384 + it * 2048); }
#define STAGE_V(KT, BB) { const u16* gv_ = vsrc + (KT) * 64;                   \
  _Pragma("unroll") for (int it = 0; it < 8; ++it)                             \
    gl_lds16(gv_ + (long)it * 32 * SQLEN, vdst + (BB) * 16384 + it * 2048); }
#define ABAR() asm volatile("s_barrier" ::: "memory")

  for (int half = 0; half < 2; ++half) {
    const int qt = half ? p : 31 - p;  // heavy tile first

    ABAR();  // prev half's LDS readers done before restaging
    const u16* qrow = qp + (long)(qt * 64 + wave * 16 + l16) * QKVW + quad * 8;
    bf16x8 qf[8];
    #pragma unroll
    for (int s = 0; s < 8; ++s)
      qf[s] = *reinterpret_cast<const bf16x8*>(qrow + s * 32);

    STAGE_K(0, 0); STAGE_V(0, 0);
    if (qt > 0) {
      STAGE_K(1, 1); STAGE_V(1, 1);
      asm volatile("s_waitcnt vmcnt(16)" ::: "memory");
    } else {
      asm volatile("s_waitcnt vmcnt(0)" ::: "memory");
    }
    ABAR();

    float m_i[4], l_i[4];
    #pragma unroll
    for (int r = 0; r < 4; ++r) { m_i[r] = -INFINITY; l_i[r] = 0.f; }
    f32x4 o[16] = {};

    for (int kt = 0; kt <= qt; ++kt) {
      const int bb = kt & 1;
      // ---- QK^T (reads Ks[bb])
      f32x4 sc[4] = {};
      __builtin_amdgcn_s_setprio(1);
      #pragma unroll
      for (int s = 0; s < 8; ++s) {
        #pragma unroll
        for (int nb = 0; nb < 4; ++nb) {
          bf16x8 kf = *reinterpret_cast<const bf16x8*>(
              &Ks[bb][nb * 16 + l16][(((s << 2) + quad) ^ sw7) * 8]);
          sc[nb] = __builtin_amdgcn_mfma_f32_16x16x32_bf16(qf[s], kf, sc[nb], 0, 0, 0);
        }
      }
      __builtin_amdgcn_s_setprio(0);
      // ---- mask + online softmax (always-rescale)
      const bool diag = (kt == qt);
      #pragma unroll
      for (int nb = 0; nb < 4; ++nb)
        #pragma unroll
        for (int r = 0; r < 4; ++r) {
          float v = sc[nb][r] * cs;
          if (diag) {
            int colL = nb * 16 + l16, rowL = wave * 16 + quad * 4 + r;
            if (colL > rowL) v = -INFINITY;
          }
          sc[nb][r] = v;
        }
      float alpha[4];
      #pragma unroll
      for (int r = 0; r < 4; ++r) {
        float t = fmaxf(fmaxf(sc[0][r], sc[1][r]), fmaxf(sc[2][r], sc[3][r]));
        #pragma unroll
        for (int d = 1; d < 16; d <<= 1) t = fmaxf(t, __shfl_xor(t, d));
        float mn = fmaxf(m_i[r], t);
        alpha[r] = exp2f(m_i[r] - mn);
        m_i[r] = mn;
      }
      #pragma unroll
      for (int r = 0; r < 4; ++r) {
        float t = 0.f;
        #pragma unroll
        for (int nb = 0; nb < 4; ++nb) {
          float pr = exp2f(sc[nb][r] - m_i[r]);
          sc[nb][r] = pr;
          t += pr;
        }
        #pragma unroll
        for (int d = 1; d < 16; d <<= 1) t += __shfl_xor(t, d);
        l_i[r] = l_i[r] * alpha[r] + t;
      }
      ABAR();  // all waves done reading Ks[bb]
      if (kt + 2 <= qt) STAGE_K(kt + 2, bb);
      // ---- P relayout (wave-private rows) + O rescale
      #pragma unroll
      for (int nb = 0; nb < 4; ++nb)
        #pragma unroll
        for (int r = 0; r < 4; ++r)
          Ps[wave * 16 + quad * 4 + r][nb * 16 + l16] = f2bf(sc[nb][r]);
      #pragma unroll
      for (int c16 = 0; c16 < 16; ++c16)
        #pragma unroll
        for (int r = 0; r < 4; ++r)
          o[c16][r] *= alpha[r];
      bf16x8 pf[2];
      #pragma unroll
      for (int s2 = 0; s2 < 2; ++s2)
        pf[s2] = *reinterpret_cast<const bf16x8*>(&Ps[wave * 16 + l16][s2 * 32 + quad * 8]);
      // ---- PV (reads Vs[bb])
      __builtin_amdgcn_s_setprio(1);
      #pragma unroll
      for (int c16 = 0; c16 < 16; ++c16) {
        #pragma unroll
        for (int s2 = 0; s2 < 2; ++s2) {
          bf16x8 vf = *reinterpret_cast<const bf16x8*>(
              &Vs[bb][c16 * 16 + l16][(((s2 << 2) + quad) ^ sw7) * 8]);
          o[c16] = __builtin_amdgcn_mfma_f32_16x16x32_bf16(pf[s2], vf, o[c16], 0, 0, 0);
        }
      }
      __builtin_amdgcn_s_setprio(0);
      if (kt < qt) {
        ABAR();  // all waves done reading Vs[bb]
        if (kt + 2 <= qt) {
          STAGE_V(kt + 2, bb);
          asm volatile("s_waitcnt vmcnt(16)" ::: "memory");
        } else {
          asm volatile("s_waitcnt vmcnt(0)" ::: "memory");
        }
        ABAR();  // tile kt+1 visible to all waves
      }
    }
    // ---- epilogue
    #pragma unroll
    for (int r = 0; r < 4; ++r) {
      float inv = 1.0f / l_i[r];
      long q = qt * 64 + wave * 16 + quad * 4 + r;
      long rowoff = ((long)b * SQLEN + q) * 4096 + h * HEADD;
      #pragma unroll
      for (int c16 = 0; c16 < 16; ++c16)
        attnout[rowoff + c16 * 16 + l16] = f2bf(o[c16][r] * inv);
    }
  }
#undef STAGE_K
#undef STAGE_V
#undef ABAR
}

// ---------------------------------------------------------------------------
extern "C" void kernel_launch(void* const* d_in, const int* in_sizes, int n_in,
                              void* d_out, int out_size, void* d_ws, size_t ws_size,
                              hipStream_t stream) {
  const float* hidden = (const float*)d_in[0];
  const int* positions = (const int*)d_in[1];
  const float* Wqkv = (const float*)d_in[2];
  const float* Wo = (const float*)d_in[3];
  float* out = (float*)d_out;
  char* ws = (char*)d_ws;

  // workspace layout (bytes), total 200 MiB:
  //   [0, 100663296)           qkv   4096x12288 bf16 (rope applied in GEMM1)
  //   [100663296, 176160768)   WqkvT 12288x3072 bf16 (dead after GEMM1):
  //     [100663296, 134217728)   attn 4096x4096 bf16
  //     [134217728, 159383552)   WoT  3072x4096 bf16
  //   [176160768, 201326592)   hiddenB 4096x3072 bf16 (dead after GEMM1)
  //   [201326592, 203423744)   rope cos/sin table 2048x128 float2
  //                            (read by GEMM1 epilogue; VT overwrites later)
  //   [176160768, 209715200)   VT 32x256x2048 bf16 (written after GEMM1)
  u16* qkv     = (u16*)(ws);
  u16* WqkvT   = (u16*)(ws + 100663296L);
  u16* attn    = (u16*)(ws + 100663296L);
  u16* WoT     = (u16*)(ws + 134217728L);
  u16* hiddenB = (u16*)(ws + 176160768L);
  u16* VT      = (u16*)(ws + 176160768L);
  float2* rtab = (float2*)(ws + 201326592L);

  f32_to_bf16<<<dim3(6144, 1, 1), 256, 0, stream>>>(hidden, hiddenB);
  rope_table<<<dim3(1024, 1, 1), 256, 0, stream>>>(rtab);
  ktranspose_f32<<<dim3(192, 48, 1), 256, 0, stream>>>(Wqkv, WqkvT, 12288, 3072);
  gemm_bt8<u16, true><<<dim3(48, 16, 1), 512, 0, stream>>>(
      hiddenB, WqkvT, qkv, 4096, 12288, 3072, rtab, positions);
  ktranspose_bf16<<<dim3(4, 32, 32), 256, 0, stream>>>(
      qkv, VT, 12288, 2048, 8192,
      25165824L, 256L, 8388608L, 524288L);
  attn_kernel<<<dim3(16, 32, 1), 256, 0, stream>>>(qkv, VT, attn);
  ktranspose_f32<<<dim3(48, 64, 1), 256, 0, stream>>>(Wo, WoT, 3072, 4096);
  gemm_bt8<float, false><<<dim3(12, 16, 1), 512, 0, stream>>>(
      attn, WoT, out, 4096, 3072, 4096, nullptr, nullptr);
}

// Round 6
// 889.743 us; speedup vs baseline: 1.1797x; 1.0897x over previous
//
#include <hip/hip_runtime.h>

#define SQLEN 2048
#define QKVW 12288
#define NHEADS 16
#define HEADD 256

typedef unsigned short u16;
typedef __bf16 bf16x8 __attribute__((ext_vector_type(8)));
typedef float f32x4 __attribute__((ext_vector_type(4)));

__device__ __forceinline__ float bf2f(u16 u) {
  union { unsigned int i; float f; } v; v.i = ((unsigned int)u) << 16; return v.f;
}
__device__ __forceinline__ u16 f2bf(float f) {
  union { float f; unsigned int i; } v; v.f = f;
  unsigned int x = v.i;
  return (u16)((x + 0x7fffu + ((x >> 16) & 1u)) >> 16);
}

// async global->LDS, 16B per lane. LDS dest must be wave-uniform base + lane*16.
__device__ __forceinline__ void gl_lds16(const u16* g, u16* l) {
  __builtin_amdgcn_global_load_lds(
      (const __attribute__((address_space(1))) void*)g,
      (__attribute__((address_space(3))) void*)l, 16, 0, 0);
}

// ---------------------------------------------------------------------------
// f32 -> bf16 elementwise convert (8 elems/thread, float4 loads).
// ---------------------------------------------------------------------------
__global__ __launch_bounds__(256) void f32_to_bf16(
    const float* __restrict__ src, u16* __restrict__ dst) {
  long i = (long)(blockIdx.x * 256 + threadIdx.x) * 8;
  float4 a = *reinterpret_cast<const float4*>(src + i);
  float4 b = *reinterpret_cast<const float4*>(src + i + 4);
  u16 tmp[8] = {f2bf(a.x), f2bf(a.y), f2bf(a.z), f2bf(a.w),
                f2bf(b.x), f2bf(b.y), f2bf(b.z), f2bf(b.w)};
  *reinterpret_cast<uint4*>(dst + i) = *reinterpret_cast<uint4*>(tmp);
}

// ---------------------------------------------------------------------------
// 64x64-tiled transpose f32 src -> bf16 dst, XOR-swizzled LDS.
// ---------------------------------------------------------------------------
__global__ __launch_bounds__(256) void ktranspose_f32(
    const float* __restrict__ src, u16* __restrict__ dst,
    int src_ld, int dst_ld) {
  __shared__ __align__(16) u16 t[64][64];
  const int c0 = blockIdx.x * 64, r0 = blockIdx.y * 64;
  const int tid = threadIdx.x;
  #pragma unroll
  for (int it = 0; it < 2; ++it) {
    int c = tid + it * 256;
    int r = c >> 3, ch = c & 7;
    const float* sp = src + (long)(r0 + r) * src_ld + c0 + ch * 8;
    float4 v0 = *reinterpret_cast<const float4*>(sp);
    float4 v1 = *reinterpret_cast<const float4*>(sp + 4);
    u16 tmp[8] = {f2bf(v0.x), f2bf(v0.y), f2bf(v0.z), f2bf(v0.w),
                  f2bf(v1.x), f2bf(v1.y), f2bf(v1.z), f2bf(v1.w)};
    int sw = ch ^ (r & 7);
    *reinterpret_cast<uint4*>(&t[r][sw * 8]) = *reinterpret_cast<uint4*>(tmp);
  }
  __syncthreads();
  #pragma unroll
  for (int it = 0; it < 2; ++it) {
    int c = tid + it * 256;
    int rr = c >> 3, ch = c & 7;
    u16 tmp[8];
    #pragma unroll
    for (int j = 0; j < 8; ++j) {
      int k = ch * 8 + j;
      int sw = (rr >> 3) ^ (k & 7);
      tmp[j] = t[k][sw * 8 + (rr & 7)];
    }
    *reinterpret_cast<uint4*>(dst + (long)(c0 + rr) * dst_ld + r0 + ch * 8) =
        *reinterpret_cast<uint4*>(tmp);
  }
}

// ---------------------------------------------------------------------------
// 64x64-tiled bf16 transpose with batch-z offsets (for V -> V^T per head).
// ---------------------------------------------------------------------------
__global__ __launch_bounds__(256) void ktranspose_bf16(
    const u16* __restrict__ src, u16* __restrict__ dst,
    int src_ld, int dst_ld, long src_off,
    long szs1, long szs2, long dzs1, long dzs2) {
  __shared__ __align__(16) u16 t[64][64];
  const int z = blockIdx.z;
  const u16* s = src + src_off + (long)(z >> 4) * szs1 + (long)(z & 15) * szs2;
  u16* d = dst + (long)(z >> 4) * dzs1 + (long)(z & 15) * dzs2;
  const int c0 = blockIdx.x * 64, r0 = blockIdx.y * 64;
  const int tid = threadIdx.x;
  #pragma unroll
  for (int it = 0; it < 2; ++it) {
    int c = tid + it * 256;
    int r = c >> 3, ch = c & 7;
    uint4 v = *reinterpret_cast<const uint4*>(s + (long)(r0 + r) * src_ld + c0 + ch * 8);
    int sw = ch ^ (r & 7);
    *reinterpret_cast<uint4*>(&t[r][sw * 8]) = v;
  }
  __syncthreads();
  #pragma unroll
  for (int it = 0; it < 2; ++it) {
    int c = tid + it * 256;
    int rr = c >> 3, ch = c & 7;
    u16 tmp[8];
    #pragma unroll
    for (int j = 0; j < 8; ++j) {
      int k = ch * 8 + j;
      int sw = (rr >> 3) ^ (k & 7);
      tmp[j] = t[k][sw * 8 + (rr & 7)];
    }
    *reinterpret_cast<uint4*>(d + (long)(c0 + rr) * dst_ld + r0 + ch * 8) =
        *reinterpret_cast<uint4*>(tmp);
  }
}

// ---------------------------------------------------------------------------
// C = A @ BT^T : 256x256 tile, BK=64, 8 waves, 8-phase schedule, XOR-swizzled
// LDS.  Proven R1 ledger (308 us / FETCH 232 MB @ GEMM1; depth-2 vmcnt(6)
// variant regressed to 342 us / 341 MB -- wider live window thrashes L2):
//   prologue: tile0 full + A0,A1(t1);  ph1(t): A2,A3(t+1); ph2(t): B0,B1(t+1);
//   ph3(t): B2,B3(t+1); ph4(t): A0,A1(t+2) into buf b, vmcnt(2).
// grid: (N/256, M/256)
// ---------------------------------------------------------------------------
template <typename OUT_T>
__global__ __launch_bounds__(512, 2) void gemm_bt8(
    const u16* __restrict__ A, const u16* __restrict__ BT, OUT_T* __restrict__ C,
    int M, int N, int K) {
  (void)M;
  __shared__ __align__(16) u16 As[2][256][64];
  __shared__ __align__(16) u16 Bs[2][256][64];
  const int tid = threadIdx.x;
  const int wave = tid >> 6, lane = tid & 63;
  const int quad = lane >> 4, l16 = lane & 15;
  const int wm = (wave >> 2) * 128, wn = (wave & 3) * 64;
  const long m0 = (long)blockIdx.y * 256, n0 = (long)blockIdx.x * 256;
  const int sw = l16 & 7;
  const int ca0 = (quad ^ sw) * 8;
  const int ca1 = ((4 + quad) ^ sw) * 8;
  const int srow = tid >> 3;
  const int sdst8 = (tid & 7) * 8;
  const int ssrc8 = ((tid & 7) ^ (srow & 7)) * 8;
  const long Kl = K;
  const u16* gA = A + (m0 + srow) * Kl + ssrc8;
  const u16* gB = BT + (n0 + srow) * Kl + ssrc8;
  const int nt = K >> 6;

  f32x4 acc[8][4] = {};
  bf16x8 af[4][2];
  bf16x8 bfr[4][2];

#define STAGE_A(BB, R, K0) \
  gl_lds16(gA + (long)((R) << 6) * Kl + (K0), &As[BB][((R) << 6) + srow][sdst8])
#define STAGE_B(BB, R, K0) \
  gl_lds16(gB + (long)((R) << 6) * Kl + (K0), &Bs[BB][((R) << 6) + srow][sdst8])
#define READ_A(BB, RBASE)                                              \
  _Pragma("unroll") for (int i4 = 0; i4 < 4; ++i4) {                   \
    const u16* p_ = &As[BB][(RBASE) + i4 * 16 + l16][0];               \
    af[i4][0] = *reinterpret_cast<const bf16x8*>(p_ + ca0);            \
    af[i4][1] = *reinterpret_cast<const bf16x8*>(p_ + ca1);            \
  }
#define READ_B(BB, JB)                                                 \
  _Pragma("unroll") for (int j2 = 0; j2 < 2; ++j2) {                   \
    const u16* p_ = &Bs[BB][wn + ((JB) + j2) * 16 + l16][0];           \
    bfr[(JB) + j2][0] = *reinterpret_cast<const bf16x8*>(p_ + ca0);    \
    bfr[(JB) + j2][1] = *reinterpret_cast<const bf16x8*>(p_ + ca1);    \
  }
#define QUADMFMA(MB, NB)                                               \
  _Pragma("unroll") for (int i4 = 0; i4 < 4; ++i4)                     \
  _Pragma("unroll") for (int j2 = 0; j2 < 2; ++j2)                     \
  _Pragma("unroll") for (int s = 0; s < 2; ++s)                        \
    acc[(MB) + i4][(NB) + j2] = __builtin_amdgcn_mfma_f32_16x16x32_bf16( \
        af[i4][s], bfr[(NB) + j2][s], acc[(MB) + i4][(NB) + j2], 0, 0, 0);
#define BAR() asm volatile("s_barrier" ::: "memory")
#define LGKM0() asm volatile("s_waitcnt lgkmcnt(0)" ::: "memory")

  // prologue: tile0 full (8 rounds) -> buf0; tile1 rounds A0,A1 -> buf1
  STAGE_A(0, 0, 0); STAGE_A(0, 1, 0); STAGE_A(0, 2, 0); STAGE_A(0, 3, 0);
  STAGE_B(0, 0, 0); STAGE_B(0, 1, 0); STAGE_B(0, 2, 0); STAGE_B(0, 3, 0);
  if (nt > 1) {
    STAGE_A(1, 0, 64); STAGE_A(1, 1, 64);
    asm volatile("s_waitcnt vmcnt(2)" ::: "memory");
  } else {
    asm volatile("s_waitcnt vmcnt(0)" ::: "memory");
  }
  BAR();

  for (int t = 0; t < nt; ++t) {
    const int b = t & 1;
    const long kn = (long)(t + 1) << 6;
    const long kn2 = (long)(t + 2) << 6;
    const bool st1 = (t + 1 < nt), st2 = (t + 2 < nt);
    // ---- phase 1: reads A(wm)+B0 (12 ds); stage A2,A3(t+1); MFMA Q(0,0)
    READ_A(b, wm);
    READ_B(b, 0);
    if (st1) { STAGE_A(b ^ 1, 2, kn); STAGE_A(b ^ 1, 3, kn); }
    BAR(); LGKM0();
    __builtin_amdgcn_s_setprio(1);
    QUADMFMA(0, 0);
    __builtin_amdgcn_s_setprio(0);
    BAR();
    // ---- phase 2: reads B2 (4 ds); stage B0,B1(t+1); MFMA Q(0,1)
    READ_B(b, 2);
    if (st1) { STAGE_B(b ^ 1, 0, kn); STAGE_B(b ^ 1, 1, kn); }
    BAR(); LGKM0();
    __builtin_amdgcn_s_setprio(1);
    QUADMFMA(0, 2);
    __builtin_amdgcn_s_setprio(0);
    BAR();
    // ---- phase 3: reads A(wm+64) (8 ds); stage B2,B3(t+1); MFMA Q(1,1)
    READ_A(b, wm + 64);
    if (st1) { STAGE_B(b ^ 1, 2, kn); STAGE_B(b ^ 1, 3, kn); }
    BAR(); LGKM0();
    __builtin_amdgcn_s_setprio(1);
    QUADMFMA(4, 2);
    __builtin_amdgcn_s_setprio(0);
    BAR();
    // ---- phase 4: no ds reads; stage A0,A1(t+2) into buf b; MFMA Q(1,0)
    if (st2) { STAGE_A(b, 0, kn2); STAGE_A(b, 1, kn2); }
    BAR();
    __builtin_amdgcn_s_setprio(1);
    QUADMFMA(4, 0);
    __builtin_amdgcn_s_setprio(0);
    if (st2)      asm volatile("s_waitcnt vmcnt(2)" ::: "memory");
    else if (st1) asm volatile("s_waitcnt vmcnt(0)" ::: "memory");
    BAR();
  }

  #pragma unroll
  for (int i = 0; i < 8; ++i)
    #pragma unroll
    for (int j = 0; j < 4; ++j) {
      long col = n0 + wn + j * 16 + l16;
      #pragma unroll
      for (int r = 0; r < 4; ++r) {
        long row = m0 + wm + i * 16 + quad * 4 + r;
        if constexpr (sizeof(OUT_T) == 4)
          C[row * (long)N + col] = acc[i][j][r];
        else
          C[row * (long)N + col] = f2bf(acc[i][j][r]);
      }
    }
#undef STAGE_A
#undef STAGE_B
#undef READ_A
#undef READ_B
#undef QUADMFMA
#undef BAR
#undef LGKM0
}

// ---------------------------------------------------------------------------
// RoPE trig table: tab[pos*128+i] = (cos, sin)(pos * theta^(-i/128)).
// ---------------------------------------------------------------------------
__global__ __launch_bounds__(256) void rope_table(float2* __restrict__ tab) {
  int idx = blockIdx.x * 256 + threadIdx.x;
  int pos = idx >> 7, i = idx & 127;
  float inv_freq = exp2f((float)i * (-13.287712379549449f / 128.0f));
  float ang = (float)pos * inv_freq;
  float sv, cv;
  sincosf(ang, &sv, &cv);
  tab[idx] = make_float2(cv, sv);
}

// ---------------------------------------------------------------------------
// NeoX RoPE in-place on q,k parts of qkv[4096][12288] (bf16), table-driven,
// 8 pairs/thread (16 B/lane loads). grid: 8192 x 256.
// ---------------------------------------------------------------------------
__global__ __launch_bounds__(256) void rope_kernel(
    u16* __restrict__ qkv, const int* __restrict__ positions,
    const float2* __restrict__ tab) {
  int idx = blockIdx.x * 256 + threadIdx.x;
  int t16 = idx & 15;          // 16 threads cover 128 pairs
  int head = (idx >> 4) & 31;
  int row = idx >> 9;
  int col = (head < NHEADS) ? head * HEADD : 4096 + (head - NHEADS) * HEADD;
  u16* p = qkv + (long)row * QKVW + col + t16 * 8;
  u16 x1[8], x2[8];
  *reinterpret_cast<uint4*>(x1) = *reinterpret_cast<const uint4*>(p);
  *reinterpret_cast<uint4*>(x2) = *reinterpret_cast<const uint4*>(p + 128);
  const float2* e = tab + (long)positions[row] * 128 + t16 * 8;
  u16 o1[8], o2[8];
  #pragma unroll
  for (int j = 0; j < 8; ++j) {
    float c = e[j].x, s = e[j].y;
    float a = bf2f(x1[j]), bb = bf2f(x2[j]);
    o1[j] = f2bf(a * c - bb * s);
    o2[j] = f2bf(bb * c + a * s);
  }
  *reinterpret_cast<uint4*>(p) = *reinterpret_cast<uint4*>(o1);
  *reinterpret_cast<uint4*>(p + 128) = *reinterpret_cast<uint4*>(o2);
}

// ---------------------------------------------------------------------------
// Flash attention, causal, load-balanced persistent blocks.
// v3: SINGLE-buffered K/V (73 KB LDS -> 2 blocks/CU, all 512 blocks
// co-resident; TLP hides what the dropped double-buffer used to).
// Software-pipelined staging without a 2nd buffer:
//   invariant at loop top: K(kt) visible, V(kt) 8 loads in flight.
//   QK^T; BAR(K readers done); issue K(kt+1)    [covered by softmax+PV]
//   softmax; vmcnt(8) drains V(kt); BAR(V visible)
//   P relayout; PV; BAR(V readers done); issue V(kt+1)
//   vmcnt(8) drains K(kt+1); BAR(K visible)     [V(kt+1) stays in flight]
// vmcnt counts incl. epilogue stores / qf loads are drained by the same
// counted waits (they only add slack, never miss a drain).
// grid: (16, B*NH), 256 threads, 2 blocks/CU.
// ---------------------------------------------------------------------------
__global__ __launch_bounds__(256, 2) void attn_kernel(
    const u16* __restrict__ qkv, const u16* __restrict__ VT,
    u16* __restrict__ attnout) {
  const int p = blockIdx.x;
  const int bh = blockIdx.y;
  const int b = bh >> 4, h = bh & 15;
  const int tid = threadIdx.x;
  const int wave = tid >> 6, lane = tid & 63;
  const int quad = lane >> 4, l16 = lane & 15;
  const int sw7 = l16 & 7;

  __shared__ __align__(16) u16 Ks[64][256];  // K tile, XOR-swizzled
  __shared__ __align__(16) u16 Vs[256][64];  // V^T tile, XOR-swizzled
  __shared__ __align__(16) u16 Ps[64][72];   // P relayout (wave-private rows)

  const u16* qp = qkv + (long)b * SQLEN * QKVW + h * HEADD;
  const u16* kp = qp + 4096;
  const u16* vtp = VT + (long)bh * HEADD * SQLEN;
  const float cs = 0.0625f * 1.4426950408889634f;  // scale * log2(e)

  // staging bases: LDS[r][c] = G[r][c ^ (r&7)] (16B-chunk XOR involution)
  const u16* ksrc = kp + (long)(tid >> 5) * QKVW + ((tid & 31) ^ ((tid >> 5) & 7)) * 8;
  const u16* vsrc = vtp + (long)(tid >> 3) * SQLEN + ((tid & 7) ^ ((tid >> 3) & 7)) * 8;
  u16* kdst = &Ks[0][0] + tid * 8;
  u16* vdst = &Vs[0][0] + tid * 8;

#define STAGE_K(KT) { const u16* gk_ = ksrc + (long)(KT) * 64 * QKVW;          \
  _Pragma("unroll") for (int it = 0; it < 8; ++it)                             \
    gl_lds16(gk_ + (long)it * 8 * QKVW, kdst + it * 2048); }
#define STAGE_V(KT) { const u16* gv_ = vsrc + (KT) * 64;                       \
  _Pragma("unroll") for (int it = 0; it < 8; ++it)                             \
    gl_lds16(gv_ + (long)it * 32 * SQLEN, vdst + it * 2048); }
#define ABAR() asm volatile("s_barrier" ::: "memory")
#define VM8()  asm volatile("s_waitcnt vmcnt(8)" ::: "memory")
#define VM0()  asm volatile("s_waitcnt vmcnt(0)" ::: "memory")

  for (int half = 0; half < 2; ++half) {
    const int qt = half ? p : 31 - p;  // heavy tile first

    ABAR();  // prev half's LDS readers done before restaging
    const u16* qrow = qp + (long)(qt * 64 + wave * 16 + l16) * QKVW + quad * 8;
    bf16x8 qf[8];
    #pragma unroll
    for (int s = 0; s < 8; ++s)
      qf[s] = *reinterpret_cast<const bf16x8*>(qrow + s * 32);

    STAGE_K(0); STAGE_V(0);
    VM8();   // K landed (drains qf loads + K; leaves V's 8 in flight)
    ABAR();  // K visible to all waves

    float m_i[4], l_i[4];
    #pragma unroll
    for (int r = 0; r < 4; ++r) { m_i[r] = -INFINITY; l_i[r] = 0.f; }
    f32x4 o[16] = {};

    for (int kt = 0; kt <= qt; ++kt) {
      const bool more = (kt < qt);
      // ---- QK^T (reads Ks) -- ds_reads consumed by MFMA issue, so all
      // LDS reads are complete before the barrier below.
      f32x4 sc[4] = {};
      __builtin_amdgcn_s_setprio(1);
      #pragma unroll
      for (int s = 0; s < 8; ++s) {
        #pragma unroll
        for (int nb = 0; nb < 4; ++nb) {
          bf16x8 kf = *reinterpret_cast<const bf16x8*>(
              &Ks[nb * 16 + l16][(((s << 2) + quad) ^ sw7) * 8]);
          sc[nb] = __builtin_amdgcn_mfma_f32_16x16x32_bf16(qf[s], kf, sc[nb], 0, 0, 0);
        }
      }
      __builtin_amdgcn_s_setprio(0);
      ABAR();                       // all waves done reading Ks
      if (more) STAGE_K(kt + 1);    // overwrite Ks; covered by softmax+PV
      // ---- mask + online softmax (always rescale)
      const bool diag = (kt == qt);
      #pragma unroll
      for (int nb = 0; nb < 4; ++nb)
        #pragma unroll
        for (int r = 0; r < 4; ++r) {
          float v = sc[nb][r] * cs;
          if (diag) {
            int colL = nb * 16 + l16, rowL = wave * 16 + quad * 4 + r;
            if (colL > rowL) v = -INFINITY;
          }
          sc[nb][r] = v;
        }
      float alpha[4];
      #pragma unroll
      for (int r = 0; r < 4; ++r) {
        float t = fmaxf(fmaxf(sc[0][r], sc[1][r]), fmaxf(sc[2][r], sc[3][r]));
        #pragma unroll
        for (int d = 1; d < 16; d <<= 1) t = fmaxf(t, __shfl_xor(t, d));
        float mn = fmaxf(m_i[r], t);
        alpha[r] = exp2f(m_i[r] - mn);
        m_i[r] = mn;
      }
      #pragma unroll
      for (int r = 0; r < 4; ++r) {
        float t = 0.f;
        #pragma unroll
        for (int nb = 0; nb < 4; ++nb) {
          float pr = exp2f(sc[nb][r] - m_i[r]);
          sc[nb][r] = pr;
          t += pr;
        }
        #pragma unroll
        for (int d = 1; d < 16; d <<= 1) t += __shfl_xor(t, d);
        l_i[r] = l_i[r] * alpha[r] + t;
      }
      // ---- V(kt) drain: vmcnt(8) leaves K(kt+1)'s 8 in flight (tail: 0)
      if (more) VM8(); else VM0();
      ABAR();                       // V visible to all waves
      // ---- P relayout (wave-private rows) + O rescale
      #pragma unroll
      for (int nb = 0; nb < 4; ++nb)
        #pragma unroll
        for (int r = 0; r < 4; ++r)
          Ps[wave * 16 + quad * 4 + r][nb * 16 + l16] = f2bf(sc[nb][r]);
      #pragma unroll
      for (int c16 = 0; c16 < 16; ++c16)
        #pragma unroll
        for (int r = 0; r < 4; ++r)
          o[c16][r] *= alpha[r];
      bf16x8 pf[2];
      #pragma unroll
      for (int s2 = 0; s2 < 2; ++s2)
        pf[s2] = *reinterpret_cast<const bf16x8*>(&Ps[wave * 16 + l16][s2 * 32 + quad * 8]);
      // ---- PV (reads Vs)
      __builtin_amdgcn_s_setprio(1);
      #pragma unroll
      for (int c16 = 0; c16 < 16; ++c16) {
        #pragma unroll
        for (int s2 = 0; s2 < 2; ++s2) {
          bf16x8 vf = *reinterpret_cast<const bf16x8*>(
              &Vs[c16 * 16 + l16][(((s2 << 2) + quad) ^ sw7) * 8]);
          o[c16] = __builtin_amdgcn_mfma_f32_16x16x32_bf16(pf[s2], vf, o[c16], 0, 0, 0);
        }
      }
      __builtin_amdgcn_s_setprio(0);
      if (more) {
        ABAR();                     // all waves done reading Vs
        STAGE_V(kt + 1);            // covered by next QK^T+softmax
        VM8();                      // K(kt+1) landed; V(kt+1) in flight
        ABAR();                     // K visible
      }
    }
    // ---- epilogue
    #pragma unroll
    for (int r = 0; r < 4; ++r) {
      float inv = 1.0f / l_i[r];
      long q = qt * 64 + wave * 16 + quad * 4 + r;
      long rowoff = ((long)b * SQLEN + q) * 4096 + h * HEADD;
      #pragma unroll
      for (int c16 = 0; c16 < 16; ++c16)
        attnout[rowoff + c16 * 16 + l16] = f2bf(o[c16][r] * inv);
    }
  }
#undef STAGE_K
#undef STAGE_V
#undef ABAR
#undef VM8
#undef VM0
}

// ---------------------------------------------------------------------------
extern "C" void kernel_launch(void* const* d_in, const int* in_sizes, int n_in,
                              void* d_out, int out_size, void* d_ws, size_t ws_size,
                              hipStream_t stream) {
  const float* hidden = (const float*)d_in[0];
  const int* positions = (const int*)d_in[1];
  const float* Wqkv = (const float*)d_in[2];
  const float* Wo = (const float*)d_in[3];
  float* out = (float*)d_out;
  char* ws = (char*)d_ws;

  // workspace layout (bytes), total 200 MiB:
  //   [0, 100663296)           qkv   4096x12288 bf16
  //   [100663296, 176160768)   WqkvT 12288x3072 bf16 (dead after GEMM1):
  //     [100663296, 134217728)   attn 4096x4096 bf16
  //     [134217728, 159383552)   WoT  3072x4096 bf16
  //   [176160768, 201326592)   hiddenB 4096x3072 bf16 (dead after GEMM1)
  //   [201326592, 203423744)   rope cos/sin table 2048x128 float2
  //                            (read by rope_kernel; VT overwrites later)
  //   [176160768, 209715200)   VT 32x256x2048 bf16 (written after rope)
  u16* qkv     = (u16*)(ws);
  u16* WqkvT   = (u16*)(ws + 100663296L);
  u16* attn    = (u16*)(ws + 100663296L);
  u16* WoT     = (u16*)(ws + 134217728L);
  u16* hiddenB = (u16*)(ws + 176160768L);
  u16* VT      = (u16*)(ws + 176160768L);
  float2* rtab = (float2*)(ws + 201326592L);

  f32_to_bf16<<<dim3(6144, 1, 1), 256, 0, stream>>>(hidden, hiddenB);
  rope_table<<<dim3(1024, 1, 1), 256, 0, stream>>>(rtab);
  ktranspose_f32<<<dim3(192, 48, 1), 256, 0, stream>>>(Wqkv, WqkvT, 12288, 3072);
  gemm_bt8<u16><<<dim3(48, 16, 1), 512, 0, stream>>>(
      hiddenB, WqkvT, qkv, 4096, 12288, 3072);
  rope_kernel<<<dim3(8192, 1, 1), 256, 0, stream>>>(qkv, positions, rtab);
  ktranspose_bf16<<<dim3(4, 32, 32), 256, 0, stream>>>(
      qkv, VT, 12288, 2048, 8192,
      25165824L, 256L, 8388608L, 524288L);
  attn_kernel<<<dim3(16, 32, 1), 256, 0, stream>>>(qkv, VT, attn);
  ktranspose_f32<<<dim3(48, 64, 1), 256, 0, stream>>>(Wo, WoT, 3072, 4096);
  gemm_bt8<float><<<dim3(12, 16, 1), 512, 0, stream>>>(
      attn, WoT, out, 4096, 3072, 4096);
}

// Round 7
// 873.429 us; speedup vs baseline: 1.2017x; 1.0187x over previous
//
#include <hip/hip_runtime.h>

#define SQLEN 2048
#define QKVW 12288
#define NHEADS 16
#define HEADD 256

typedef unsigned short u16;
typedef __bf16 bf16x8 __attribute__((ext_vector_type(8)));
typedef float f32x4 __attribute__((ext_vector_type(4)));

__device__ __forceinline__ float bf2f(u16 u) {
  union { unsigned int i; float f; } v; v.i = ((unsigned int)u) << 16; return v.f;
}
__device__ __forceinline__ u16 f2bf(float f) {
  union { float f; unsigned int i; } v; v.f = f;
  unsigned int x = v.i;
  return (u16)((x + 0x7fffu + ((x >> 16) & 1u)) >> 16);
}

// async global->LDS, 16B per lane. LDS dest must be wave-uniform base + lane*16.
__device__ __forceinline__ void gl_lds16(const u16* g, u16* l) {
  __builtin_amdgcn_global_load_lds(
      (const __attribute__((address_space(1))) void*)g,
      (__attribute__((address_space(3))) void*)l, 16, 0, 0);
}

// ---------------------------------------------------------------------------
// f32 -> bf16 elementwise convert (8 elems/thread, float4 loads).
// ---------------------------------------------------------------------------
__global__ __launch_bounds__(256) void f32_to_bf16(
    const float* __restrict__ src, u16* __restrict__ dst) {
  long i = (long)(blockIdx.x * 256 + threadIdx.x) * 8;
  float4 a = *reinterpret_cast<const float4*>(src + i);
  float4 b = *reinterpret_cast<const float4*>(src + i + 4);
  u16 tmp[8] = {f2bf(a.x), f2bf(a.y), f2bf(a.z), f2bf(a.w),
                f2bf(b.x), f2bf(b.y), f2bf(b.z), f2bf(b.w)};
  *reinterpret_cast<uint4*>(dst + i) = *reinterpret_cast<uint4*>(tmp);
}

// ---------------------------------------------------------------------------
// 64x64-tiled transpose f32 src -> bf16 dst, XOR-swizzled LDS.
// ---------------------------------------------------------------------------
__global__ __launch_bounds__(256) void ktranspose_f32(
    const float* __restrict__ src, u16* __restrict__ dst,
    int src_ld, int dst_ld) {
  __shared__ __align__(16) u16 t[64][64];
  const int c0 = blockIdx.x * 64, r0 = blockIdx.y * 64;
  const int tid = threadIdx.x;
  #pragma unroll
  for (int it = 0; it < 2; ++it) {
    int c = tid + it * 256;
    int r = c >> 3, ch = c & 7;
    const float* sp = src + (long)(r0 + r) * src_ld + c0 + ch * 8;
    float4 v0 = *reinterpret_cast<const float4*>(sp);
    float4 v1 = *reinterpret_cast<const float4*>(sp + 4);
    u16 tmp[8] = {f2bf(v0.x), f2bf(v0.y), f2bf(v0.z), f2bf(v0.w),
                  f2bf(v1.x), f2bf(v1.y), f2bf(v1.z), f2bf(v1.w)};
    int sw = ch ^ (r & 7);
    *reinterpret_cast<uint4*>(&t[r][sw * 8]) = *reinterpret_cast<uint4*>(tmp);
  }
  __syncthreads();
  #pragma unroll
  for (int it = 0; it < 2; ++it) {
    int c = tid + it * 256;
    int rr = c >> 3, ch = c & 7;
    u16 tmp[8];
    #pragma unroll
    for (int j = 0; j < 8; ++j) {
      int k = ch * 8 + j;
      int sw = (rr >> 3) ^ (k & 7);
      tmp[j] = t[k][sw * 8 + (rr & 7)];
    }
    *reinterpret_cast<uint4*>(dst + (long)(c0 + rr) * dst_ld + r0 + ch * 8) =
        *reinterpret_cast<uint4*>(tmp);
  }
}

// ---------------------------------------------------------------------------
// 64x64-tiled bf16 transpose with batch-z offsets (for V -> V^T per head).
// ---------------------------------------------------------------------------
__global__ __launch_bounds__(256) void ktranspose_bf16(
    const u16* __restrict__ src, u16* __restrict__ dst,
    int src_ld, int dst_ld, long src_off,
    long szs1, long szs2, long dzs1, long dzs2) {
  __shared__ __align__(16) u16 t[64][64];
  const int z = blockIdx.z;
  const u16* s = src + src_off + (long)(z >> 4) * szs1 + (long)(z & 15) * szs2;
  u16* d = dst + (long)(z >> 4) * dzs1 + (long)(z & 15) * dzs2;
  const int c0 = blockIdx.x * 64, r0 = blockIdx.y * 64;
  const int tid = threadIdx.x;
  #pragma unroll
  for (int it = 0; it < 2; ++it) {
    int c = tid + it * 256;
    int r = c >> 3, ch = c & 7;
    uint4 v = *reinterpret_cast<const uint4*>(s + (long)(r0 + r) * src_ld + c0 + ch * 8);
    int sw = ch ^ (r & 7);
    *reinterpret_cast<uint4*>(&t[r][sw * 8]) = v;
  }
  __syncthreads();
  #pragma unroll
  for (int it = 0; it < 2; ++it) {
    int c = tid + it * 256;
    int rr = c >> 3, ch = c & 7;
    u16 tmp[8];
    #pragma unroll
    for (int j = 0; j < 8; ++j) {
      int k = ch * 8 + j;
      int sw = (rr >> 3) ^ (k & 7);
      tmp[j] = t[k][sw * 8 + (rr & 7)];
    }
    *reinterpret_cast<uint4*>(d + (long)(c0 + rr) * dst_ld + r0 + ch * 8) =
        *reinterpret_cast<uint4*>(tmp);
  }
}

// ---------------------------------------------------------------------------
// C = A @ BT^T : 256x256 tile, BK=64, 8 waves, 8-phase schedule, XOR-swizzled
// LDS.  Proven R1 ledger (306 us / MfmaUtil 44 @ GEMM1):
//   prologue: tile0 full + A0,A1(t1);  ph1(t): A2,A3(t+1); ph2(t): B0,B1(t+1);
//   ph3(t): B2,B3(t+1); ph4(t): A0,A1(t+2) into buf b, vmcnt(2).
// grid: (N/256, M/256)
// ---------------------------------------------------------------------------
template <typename OUT_T>
__global__ __launch_bounds__(512, 2) void gemm_bt8(
    const u16* __restrict__ A, const u16* __restrict__ BT, OUT_T* __restrict__ C,
    int M, int N, int K) {
  (void)M;
  __shared__ __align__(16) u16 As[2][256][64];
  __shared__ __align__(16) u16 Bs[2][256][64];
  const int tid = threadIdx.x;
  const int wave = tid >> 6, lane = tid & 63;
  const int quad = lane >> 4, l16 = lane & 15;
  const int wm = (wave >> 2) * 128, wn = (wave & 3) * 64;
  const long m0 = (long)blockIdx.y * 256, n0 = (long)blockIdx.x * 256;
  const int sw = l16 & 7;
  const int ca0 = (quad ^ sw) * 8;
  const int ca1 = ((4 + quad) ^ sw) * 8;
  const int srow = tid >> 3;
  const int sdst8 = (tid & 7) * 8;
  const int ssrc8 = ((tid & 7) ^ (srow & 7)) * 8;
  const long Kl = K;
  const u16* gA = A + (m0 + srow) * Kl + ssrc8;
  const u16* gB = BT + (n0 + srow) * Kl + ssrc8;
  const int nt = K >> 6;

  f32x4 acc[8][4] = {};
  bf16x8 af[4][2];
  bf16x8 bfr[4][2];

#define STAGE_A(BB, R, K0) \
  gl_lds16(gA + (long)((R) << 6) * Kl + (K0), &As[BB][((R) << 6) + srow][sdst8])
#define STAGE_B(BB, R, K0) \
  gl_lds16(gB + (long)((R) << 6) * Kl + (K0), &Bs[BB][((R) << 6) + srow][sdst8])
#define READ_A(BB, RBASE)                                              \
  _Pragma("unroll") for (int i4 = 0; i4 < 4; ++i4) {                   \
    const u16* p_ = &As[BB][(RBASE) + i4 * 16 + l16][0];               \
    af[i4][0] = *reinterpret_cast<const bf16x8*>(p_ + ca0);            \
    af[i4][1] = *reinterpret_cast<const bf16x8*>(p_ + ca1);            \
  }
#define READ_B(BB, JB)                                                 \
  _Pragma("unroll") for (int j2 = 0; j2 < 2; ++j2) {                   \
    const u16* p_ = &Bs[BB][wn + ((JB) + j2) * 16 + l16][0];           \
    bfr[(JB) + j2][0] = *reinterpret_cast<const bf16x8*>(p_ + ca0);    \
    bfr[(JB) + j2][1] = *reinterpret_cast<const bf16x8*>(p_ + ca1);    \
  }
#define QUADMFMA(MB, NB)                                               \
  _Pragma("unroll") for (int i4 = 0; i4 < 4; ++i4)                     \
  _Pragma("unroll") for (int j2 = 0; j2 < 2; ++j2)                     \
  _Pragma("unroll") for (int s = 0; s < 2; ++s)                        \
    acc[(MB) + i4][(NB) + j2] = __builtin_amdgcn_mfma_f32_16x16x32_bf16( \
        af[i4][s], bfr[(NB) + j2][s], acc[(MB) + i4][(NB) + j2], 0, 0, 0);
#define BAR() asm volatile("s_barrier" ::: "memory")
#define LGKM0() asm volatile("s_waitcnt lgkmcnt(0)" ::: "memory")

  // prologue: tile0 full (8 rounds) -> buf0; tile1 rounds A0,A1 -> buf1
  STAGE_A(0, 0, 0); STAGE_A(0, 1, 0); STAGE_A(0, 2, 0); STAGE_A(0, 3, 0);
  STAGE_B(0, 0, 0); STAGE_B(0, 1, 0); STAGE_B(0, 2, 0); STAGE_B(0, 3, 0);
  if (nt > 1) {
    STAGE_A(1, 0, 64); STAGE_A(1, 1, 64);
    asm volatile("s_waitcnt vmcnt(2)" ::: "memory");
  } else {
    asm volatile("s_waitcnt vmcnt(0)" ::: "memory");
  }
  BAR();

  for (int t = 0; t < nt; ++t) {
    const int b = t & 1;
    const long kn = (long)(t + 1) << 6;
    const long kn2 = (long)(t + 2) << 6;
    const bool st1 = (t + 1 < nt), st2 = (t + 2 < nt);
    // ---- phase 1: reads A(wm)+B0 (12 ds); stage A2,A3(t+1); MFMA Q(0,0)
    READ_A(b, wm);
    READ_B(b, 0);
    if (st1) { STAGE_A(b ^ 1, 2, kn); STAGE_A(b ^ 1, 3, kn); }
    BAR(); LGKM0();
    __builtin_amdgcn_s_setprio(1);
    QUADMFMA(0, 0);
    __builtin_amdgcn_s_setprio(0);
    BAR();
    // ---- phase 2: reads B2 (4 ds); stage B0,B1(t+1); MFMA Q(0,1)
    READ_B(b, 2);
    if (st1) { STAGE_B(b ^ 1, 0, kn); STAGE_B(b ^ 1, 1, kn); }
    BAR(); LGKM0();
    __builtin_amdgcn_s_setprio(1);
    QUADMFMA(0, 2);
    __builtin_amdgcn_s_setprio(0);
    BAR();
    // ---- phase 3: reads A(wm+64) (8 ds); stage B2,B3(t+1); MFMA Q(1,1)
    READ_A(b, wm + 64);
    if (st1) { STAGE_B(b ^ 1, 2, kn); STAGE_B(b ^ 1, 3, kn); }
    BAR(); LGKM0();
    __builtin_amdgcn_s_setprio(1);
    QUADMFMA(4, 2);
    __builtin_amdgcn_s_setprio(0);
    BAR();
    // ---- phase 4: no ds reads; stage A0,A1(t+2) into buf b; MFMA Q(1,0)
    if (st2) { STAGE_A(b, 0, kn2); STAGE_A(b, 1, kn2); }
    BAR();
    __builtin_amdgcn_s_setprio(1);
    QUADMFMA(4, 0);
    __builtin_amdgcn_s_setprio(0);
    if (st2)      asm volatile("s_waitcnt vmcnt(2)" ::: "memory");
    else if (st1) asm volatile("s_waitcnt vmcnt(0)" ::: "memory");
    BAR();
  }

  #pragma unroll
  for (int i = 0; i < 8; ++i)
    #pragma unroll
    for (int j = 0; j < 4; ++j) {
      long col = n0 + wn + j * 16 + l16;
      #pragma unroll
      for (int r = 0; r < 4; ++r) {
        long row = m0 + wm + i * 16 + quad * 4 + r;
        if constexpr (sizeof(OUT_T) == 4)
          C[row * (long)N + col] = acc[i][j][r];
        else
          C[row * (long)N + col] = f2bf(acc[i][j][r]);
      }
    }
#undef STAGE_A
#undef STAGE_B
#undef READ_A
#undef READ_B
#undef QUADMFMA
#undef BAR
#undef LGKM0
}

// ---------------------------------------------------------------------------
// GEMM2 variant: C = A @ BT^T with 256(M)x192(N) tiles so the grid is
// (3072/192, 4096/256) = 16x16 = 256 blocks = exactly 1 block/CU, 1 round
// (the 256x256 tiling gave 192 blocks -> 64 CUs idle the whole dispatch).
// 8 waves as 4M x 2N: per wave 64x96, acc[4][6], 12 MFMA/phase.
// 7 staging rounds per K-tile (4 A + 3 B), R1-style ledger:
//   prologue: tile0 all 7 + A0,A1(t1), vmcnt(2);
//   ph1: A2,A3(t+1); ph2: B0,B1(t+1); ph3: B2(t+1); ph4: A0,A1(t+2), vmcnt(2)
//   (end-of-iter outstanding 9, vmcnt(2) drains exactly t+1's 7).
// A-rounds 0,1 of buf b: last ds_read in ph3 (rows wm+32..), restaged ph4
// after ph3's closing barrier -> safe. LDS 112 KB.
// grid: (N/192, M/256)
// ---------------------------------------------------------------------------
__global__ __launch_bounds__(512, 1) void gemm_bt8_n192(
    const u16* __restrict__ A, const u16* __restrict__ BT, float* __restrict__ C,
    int M, int N, int K) {
  (void)M;
  __shared__ __align__(16) u16 As[2][256][64];
  __shared__ __align__(16) u16 Bs[2][192][64];
  const int tid = threadIdx.x;
  const int wave = tid >> 6, lane = tid & 63;
  const int quad = lane >> 4, l16 = lane & 15;
  const int wm = (wave >> 1) * 64, wn = (wave & 1) * 96;
  const long m0 = (long)blockIdx.y * 256, n0 = (long)blockIdx.x * 192;
  const int sw = l16 & 7;
  const int ca0 = (quad ^ sw) * 8;
  const int ca1 = ((4 + quad) ^ sw) * 8;
  const int srow = tid >> 3;
  const int sdst8 = (tid & 7) * 8;
  const int ssrc8 = ((tid & 7) ^ (srow & 7)) * 8;
  const long Kl = K;
  const u16* gA = A + (m0 + srow) * Kl + ssrc8;
  const u16* gB = BT + (n0 + srow) * Kl + ssrc8;
  const int nt = K >> 6;

  f32x4 acc[4][6] = {};
  bf16x8 af[2][2];   // current M-half (2 frags of 16 rows)
  bf16x8 bfr[6][2];  // all 6 B col-frags for the K-tile

#define STAGE_A(BB, R, K0) \
  gl_lds16(gA + (long)((R) << 6) * Kl + (K0), &As[BB][((R) << 6) + srow][sdst8])
#define STAGE_B(BB, R, K0) \
  gl_lds16(gB + (long)((R) << 6) * Kl + (K0), &Bs[BB][((R) << 6) + srow][sdst8])
#define READ_A2(BB, RBASE)                                             \
  _Pragma("unroll") for (int i4 = 0; i4 < 2; ++i4) {                   \
    const u16* p_ = &As[BB][(RBASE) + i4 * 16 + l16][0];               \
    af[i4][0] = *reinterpret_cast<const bf16x8*>(p_ + ca0);            \
    af[i4][1] = *reinterpret_cast<const bf16x8*>(p_ + ca1);            \
  }
#define READ_B3(BB, JB)                                                \
  _Pragma("unroll") for (int j3 = 0; j3 < 3; ++j3) {                   \
    const u16* p_ = &Bs[BB][wn + ((JB) + j3) * 16 + l16][0];           \
    bfr[(JB) + j3][0] = *reinterpret_cast<const bf16x8*>(p_ + ca0);    \
    bfr[(JB) + j3][1] = *reinterpret_cast<const bf16x8*>(p_ + ca1);    \
  }
#define QMFMA(IB, JB)                                                  \
  _Pragma("unroll") for (int i4 = 0; i4 < 2; ++i4)                     \
  _Pragma("unroll") for (int j3 = 0; j3 < 3; ++j3)                     \
  _Pragma("unroll") for (int s = 0; s < 2; ++s)                        \
    acc[(IB) + i4][(JB) + j3] = __builtin_amdgcn_mfma_f32_16x16x32_bf16( \
        af[i4][s], bfr[(JB) + j3][s], acc[(IB) + i4][(JB) + j3], 0, 0, 0);
#define BAR() asm volatile("s_barrier" ::: "memory")
#define LGKM0() asm volatile("s_waitcnt lgkmcnt(0)" ::: "memory")

  // prologue: tile0 full (7 rounds) -> buf0; tile1 rounds A0,A1 -> buf1
  STAGE_A(0, 0, 0); STAGE_A(0, 1, 0); STAGE_A(0, 2, 0); STAGE_A(0, 3, 0);
  STAGE_B(0, 0, 0); STAGE_B(0, 1, 0); STAGE_B(0, 2, 0);
  if (nt > 1) {
    STAGE_A(1, 0, 64); STAGE_A(1, 1, 64);
    asm volatile("s_waitcnt vmcnt(2)" ::: "memory");
  } else {
    asm volatile("s_waitcnt vmcnt(0)" ::: "memory");
  }
  BAR();

  for (int t = 0; t < nt; ++t) {
    const int b = t & 1;
    const long kn = (long)(t + 1) << 6;
    const long kn2 = (long)(t + 2) << 6;
    const bool st1 = (t + 1 < nt), st2 = (t + 2 < nt);
    // ---- phase 1: reads A(wm) half0 (4 ds) + B j0-2 (6 ds); stage A2,A3(t+1)
    READ_A2(b, wm);
    READ_B3(b, 0);
    if (st1) { STAGE_A(b ^ 1, 2, kn); STAGE_A(b ^ 1, 3, kn); }
    BAR(); LGKM0();
    __builtin_amdgcn_s_setprio(1);
    QMFMA(0, 0);
    __builtin_amdgcn_s_setprio(0);
    BAR();
    // ---- phase 2: reads B j3-5 (6 ds); stage B0,B1(t+1)
    READ_B3(b, 3);
    if (st1) { STAGE_B(b ^ 1, 0, kn); STAGE_B(b ^ 1, 1, kn); }
    BAR(); LGKM0();
    __builtin_amdgcn_s_setprio(1);
    QMFMA(0, 3);
    __builtin_amdgcn_s_setprio(0);
    BAR();
    // ---- phase 3: reads A(wm+32) half1 (4 ds); stage B2(t+1)
    READ_A2(b, wm + 32);
    if (st1) { STAGE_B(b ^ 1, 2, kn); }
    BAR(); LGKM0();
    __builtin_amdgcn_s_setprio(1);
    QMFMA(2, 3);
    __builtin_amdgcn_s_setprio(0);
    BAR();
    // ---- phase 4: no ds reads; stage A0,A1(t+2) into buf b
    if (st2) { STAGE_A(b, 0, kn2); STAGE_A(b, 1, kn2); }
    BAR();
    __builtin_amdgcn_s_setprio(1);
    QMFMA(2, 0);
    __builtin_amdgcn_s_setprio(0);
    if (st2)      asm volatile("s_waitcnt vmcnt(2)" ::: "memory");
    else if (st1) asm volatile("s_waitcnt vmcnt(0)" ::: "memory");
    BAR();
  }

  #pragma unroll
  for (int i = 0; i < 4; ++i)
    #pragma unroll
    for (int j = 0; j < 6; ++j) {
      long col = n0 + wn + j * 16 + l16;
      #pragma unroll
      for (int r = 0; r < 4; ++r) {
        long row = m0 + wm + i * 16 + quad * 4 + r;
        C[row * (long)N + col] = acc[i][j][r];
      }
    }
#undef STAGE_A
#undef STAGE_B
#undef READ_A2
#undef READ_B3
#undef QMFMA
#undef BAR
#undef LGKM0
}

// ---------------------------------------------------------------------------
// RoPE trig table: tab[pos*128+i] = (cos, sin)(pos * theta^(-i/128)).
// ---------------------------------------------------------------------------
__global__ __launch_bounds__(256) void rope_table(float2* __restrict__ tab) {
  int idx = blockIdx.x * 256 + threadIdx.x;
  int pos = idx >> 7, i = idx & 127;
  float inv_freq = exp2f((float)i * (-13.287712379549449f / 128.0f));
  float ang = (float)pos * inv_freq;
  float sv, cv;
  sincosf(ang, &sv, &cv);
  tab[idx] = make_float2(cv, sv);
}

// ---------------------------------------------------------------------------
// NeoX RoPE in-place on q,k parts of qkv[4096][12288] (bf16), table-driven,
// 8 pairs/thread (16 B/lane loads). grid: 8192 x 256.
// ---------------------------------------------------------------------------
__global__ __launch_bounds__(256) void rope_kernel(
    u16* __restrict__ qkv, const int* __restrict__ positions,
    const float2* __restrict__ tab) {
  int idx = blockIdx.x * 256 + threadIdx.x;
  int t16 = idx & 15;          // 16 threads cover 128 pairs
  int head = (idx >> 4) & 31;
  int row = idx >> 9;
  int col = (head < NHEADS) ? head * HEADD : 4096 + (head - NHEADS) * HEADD;
  u16* p = qkv + (long)row * QKVW + col + t16 * 8;
  u16 x1[8], x2[8];
  *reinterpret_cast<uint4*>(x1) = *reinterpret_cast<const uint4*>(p);
  *reinterpret_cast<uint4*>(x2) = *reinterpret_cast<const uint4*>(p + 128);
  const float2* e = tab + (long)positions[row] * 128 + t16 * 8;
  u16 o1[8], o2[8];
  #pragma unroll
  for (int j = 0; j < 8; ++j) {
    float c = e[j].x, s = e[j].y;
    float a = bf2f(x1[j]), bb = bf2f(x2[j]);
    o1[j] = f2bf(a * c - bb * s);
    o2[j] = f2bf(bb * c + a * s);
  }
  *reinterpret_cast<uint4*>(p) = *reinterpret_cast<uint4*>(o1);
  *reinterpret_cast<uint4*>(p + 128) = *reinterpret_cast<uint4*>(o2);
}

// ---------------------------------------------------------------------------
// Flash attention, causal, load-balanced persistent blocks.
// SINGLE-buffered K/V (73 KB LDS -> 2 blocks/CU), software-pipelined staging:
//   invariant at loop top: K(kt) visible, V(kt) 8 loads in flight.
//   QK^T; BAR(K readers done); issue K(kt+1)    [covered by softmax+PV]
//   softmax; vmcnt(8) drains V(kt); BAR(V visible)
//   P relayout; PV; BAR(V readers done); issue V(kt+1)
//   vmcnt(8) drains K(kt+1); BAR(K visible)     [V(kt+1) stays in flight]
// grid: (16, B*NH), 256 threads, 2 blocks/CU.
// ---------------------------------------------------------------------------
__global__ __launch_bounds__(256, 2) void attn_kernel(
    const u16* __restrict__ qkv, const u16* __restrict__ VT,
    u16* __restrict__ attnout) {
  const int p = blockIdx.x;
  const int bh = blockIdx.y;
  const int b = bh >> 4, h = bh & 15;
  const int tid = threadIdx.x;
  const int wave = tid >> 6, lane = tid & 63;
  const int quad = lane >> 4, l16 = lane & 15;
  const int sw7 = l16 & 7;

  __shared__ __align__(16) u16 Ks[64][256];  // K tile, XOR-swizzled
  __shared__ __align__(16) u16 Vs[256][64];  // V^T tile, XOR-swizzled
  __shared__ __align__(16) u16 Ps[64][72];   // P relayout (wave-private rows)

  const u16* qp = qkv + (long)b * SQLEN * QKVW + h * HEADD;
  const u16* kp = qp + 4096;
  const u16* vtp = VT + (long)bh * HEADD * SQLEN;
  const float cs = 0.0625f * 1.4426950408889634f;  // scale * log2(e)

  // staging bases: LDS[r][c] = G[r][c ^ (r&7)] (16B-chunk XOR involution)
  const u16* ksrc = kp + (long)(tid >> 5) * QKVW + ((tid & 31) ^ ((tid >> 5) & 7)) * 8;
  const u16* vsrc = vtp + (long)(tid >> 3) * SQLEN + ((tid & 7) ^ ((tid >> 3) & 7)) * 8;
  u16* kdst = &Ks[0][0] + tid * 8;
  u16* vdst = &Vs[0][0] + tid * 8;

#define STAGE_K(KT) { const u16* gk_ = ksrc + (long)(KT) * 64 * QKVW;          \
  _Pragma("unroll") for (int it = 0; it < 8; ++it)                             \
    gl_lds16(gk_ + (long)it * 8 * QKVW, kdst + it * 2048); }
#define STAGE_V(KT) { const u16* gv_ = vsrc + (KT) * 64;                       \
  _Pragma("unroll") for (int it = 0; it < 8; ++it)                             \
    gl_lds16(gv_ + (long)it * 32 * SQLEN, vdst + it * 2048); }
#define ABAR() asm volatile("s_barrier" ::: "memory")
#define VM8()  asm volatile("s_waitcnt vmcnt(8)" ::: "memory")
#define VM0()  asm volatile("s_waitcnt vmcnt(0)" ::: "memory")

  for (int half = 0; half < 2; ++half) {
    const int qt = half ? p : 31 - p;  // heavy tile first

    ABAR();  // prev half's LDS readers done before restaging
    const u16* qrow = qp + (long)(qt * 64 + wave * 16 + l16) * QKVW + quad * 8;
    bf16x8 qf[8];
    #pragma unroll
    for (int s = 0; s < 8; ++s)
      qf[s] = *reinterpret_cast<const bf16x8*>(qrow + s * 32);

    STAGE_K(0); STAGE_V(0);
    VM8();   // K landed (drains qf loads + K; leaves V's 8 in flight)
    ABAR();  // K visible to all waves

    float m_i[4], l_i[4];
    #pragma unroll
    for (int r = 0; r < 4; ++r) { m_i[r] = -INFINITY; l_i[r] = 0.f; }
    f32x4 o[16] = {};

    for (int kt = 0; kt <= qt; ++kt) {
      const bool more = (kt < qt);
      // ---- QK^T (reads Ks)
      f32x4 sc[4] = {};
      __builtin_amdgcn_s_setprio(1);
      #pragma unroll
      for (int s = 0; s < 8; ++s) {
        #pragma unroll
        for (int nb = 0; nb < 4; ++nb) {
          bf16x8 kf = *reinterpret_cast<const bf16x8*>(
              &Ks[nb * 16 + l16][(((s << 2) + quad) ^ sw7) * 8]);
          sc[nb] = __builtin_amdgcn_mfma_f32_16x16x32_bf16(qf[s], kf, sc[nb], 0, 0, 0);
        }
      }
      __builtin_amdgcn_s_setprio(0);
      ABAR();                       // all waves done reading Ks
      if (more) STAGE_K(kt + 1);    // overwrite Ks; covered by softmax+PV
      // ---- mask + online softmax (always rescale)
      const bool diag = (kt == qt);
      #pragma unroll
      for (int nb = 0; nb < 4; ++nb)
        #pragma unroll
        for (int r = 0; r < 4; ++r) {
          float v = sc[nb][r] * cs;
          if (diag) {
            int colL = nb * 16 + l16, rowL = wave * 16 + quad * 4 + r;
            if (colL > rowL) v = -INFINITY;
          }
          sc[nb][r] = v;
        }
      float alpha[4];
      #pragma unroll
      for (int r = 0; r < 4; ++r) {
        float t = fmaxf(fmaxf(sc[0][r], sc[1][r]), fmaxf(sc[2][r], sc[3][r]));
        #pragma unroll
        for (int d = 1; d < 16; d <<= 1) t = fmaxf(t, __shfl_xor(t, d));
        float mn = fmaxf(m_i[r], t);
        alpha[r] = exp2f(m_i[r] - mn);
        m_i[r] = mn;
      }
      #pragma unroll
      for (int r = 0; r < 4; ++r) {
        float t = 0.f;
        #pragma unroll
        for (int nb = 0; nb < 4; ++nb) {
          float pr = exp2f(sc[nb][r] - m_i[r]);
          sc[nb][r] = pr;
          t += pr;
        }
        #pragma unroll
        for (int d = 1; d < 16; d <<= 1) t += __shfl_xor(t, d);
        l_i[r] = l_i[r] * alpha[r] + t;
      }
      // ---- V(kt) drain: vmcnt(8) leaves K(kt+1)'s 8 in flight (tail: 0)
      if (more) VM8(); else VM0();
      ABAR();                       // V visible to all waves
      // ---- P relayout (wave-private rows) + O rescale
      #pragma unroll
      for (int nb = 0; nb < 4; ++nb)
        #pragma unroll
        for (int r = 0; r < 4; ++r)
          Ps[wave * 16 + quad * 4 + r][nb * 16 + l16] = f2bf(sc[nb][r]);
      #pragma unroll
      for (int c16 = 0; c16 < 16; ++c16)
        #pragma unroll
        for (int r = 0; r < 4; ++r)
          o[c16][r] *= alpha[r];
      bf16x8 pf[2];
      #pragma unroll
      for (int s2 = 0; s2 < 2; ++s2)
        pf[s2] = *reinterpret_cast<const bf16x8*>(&Ps[wave * 16 + l16][s2 * 32 + quad * 8]);
      // ---- PV (reads Vs)
      __builtin_amdgcn_s_setprio(1);
      #pragma unroll
      for (int c16 = 0; c16 < 16; ++c16) {
        #pragma unroll
        for (int s2 = 0; s2 < 2; ++s2) {
          bf16x8 vf = *reinterpret_cast<const bf16x8*>(
              &Vs[c16 * 16 + l16][(((s2 << 2) + quad) ^ sw7) * 8]);
          o[c16] = __builtin_amdgcn_mfma_f32_16x16x32_bf16(pf[s2], vf, o[c16], 0, 0, 0);
        }
      }
      __builtin_amdgcn_s_setprio(0);
      if (more) {
        ABAR();                     // all waves done reading Vs
        STAGE_V(kt + 1);            // covered by next QK^T+softmax
        VM8();                      // K(kt+1) landed; V(kt+1) in flight
        ABAR();                     // K visible
      }
    }
    // ---- epilogue
    #pragma unroll
    for (int r = 0; r < 4; ++r) {
      float inv = 1.0f / l_i[r];
      long q = qt * 64 + wave * 16 + quad * 4 + r;
      long rowoff = ((long)b * SQLEN + q) * 4096 + h * HEADD;
      #pragma unroll
      for (int c16 = 0; c16 < 16; ++c16)
        attnout[rowoff + c16 * 16 + l16] = f2bf(o[c16][r] * inv);
    }
  }
#undef STAGE_K
#undef STAGE_V
#undef ABAR
#undef VM8
#undef VM0
}

// ---------------------------------------------------------------------------
extern "C" void kernel_launch(void* const* d_in, const int* in_sizes, int n_in,
                              void* d_out, int out_size, void* d_ws, size_t ws_size,
                              hipStream_t stream) {
  const float* hidden = (const float*)d_in[0];
  const int* positions = (const int*)d_in[1];
  const float* Wqkv = (const float*)d_in[2];
  const float* Wo = (const float*)d_in[3];
  float* out = (float*)d_out;
  char* ws = (char*)d_ws;

  // workspace layout (bytes), total 200 MiB:
  //   [0, 100663296)           qkv   4096x12288 bf16
  //   [100663296, 176160768)   WqkvT 12288x3072 bf16 (dead after GEMM1):
  //     [100663296, 134217728)   attn 4096x4096 bf16
  //     [134217728, 159383552)   WoT  3072x4096 bf16
  //   [176160768, 201326592)   hiddenB 4096x3072 bf16 (dead after GEMM1)
  //   [201326592, 203423744)   rope cos/sin table 2048x128 float2
  //                            (read by rope_kernel; VT overwrites later)
  //   [176160768, 209715200)   VT 32x256x2048 bf16 (written after rope)
  u16* qkv     = (u16*)(ws);
  u16* WqkvT   = (u16*)(ws + 100663296L);
  u16* attn    = (u16*)(ws + 100663296L);
  u16* WoT     = (u16*)(ws + 134217728L);
  u16* hiddenB = (u16*)(ws + 176160768L);
  u16* VT      = (u16*)(ws + 176160768L);
  float2* rtab = (float2*)(ws + 201326592L);

  f32_to_bf16<<<dim3(6144, 1, 1), 256, 0, stream>>>(hidden, hiddenB);
  rope_table<<<dim3(1024, 1, 1), 256, 0, stream>>>(rtab);
  ktranspose_f32<<<dim3(192, 48, 1), 256, 0, stream>>>(Wqkv, WqkvT, 12288, 3072);
  gemm_bt8<u16><<<dim3(48, 16, 1), 512, 0, stream>>>(
      hiddenB, WqkvT, qkv, 4096, 12288, 3072);
  rope_kernel<<<dim3(8192, 1, 1), 256, 0, stream>>>(qkv, positions, rtab);
  ktranspose_bf16<<<dim3(4, 32, 32), 256, 0, stream>>>(
      qkv, VT, 12288, 2048, 8192,
      25165824L, 256L, 8388608L, 524288L);
  attn_kernel<<<dim3(16, 32, 1), 256, 0, stream>>>(qkv, VT, attn);
  ktranspose_f32<<<dim3(48, 64, 1), 256, 0, stream>>>(Wo, WoT, 3072, 4096);
  gemm_bt8_n192<<<dim3(16, 16, 1), 512, 0, stream>>>(
      attn, WoT, out, 4096, 3072, 4096);
}

// Round 8
// 834.510 us; speedup vs baseline: 1.2578x; 1.0466x over previous
//
#include <hip/hip_runtime.h>

#define SQLEN 2048
#define QKVW 12288
#define NHEADS 16
#define HEADD 256

typedef unsigned short u16;
typedef __bf16 bf16x8 __attribute__((ext_vector_type(8)));
typedef float f32x4 __attribute__((ext_vector_type(4)));

__device__ __forceinline__ float bf2f(u16 u) {
  union { unsigned int i; float f; } v; v.i = ((unsigned int)u) << 16; return v.f;
}
__device__ __forceinline__ u16 f2bf(float f) {
  union { float f; unsigned int i; } v; v.f = f;
  unsigned int x = v.i;
  return (u16)((x + 0x7fffu + ((x >> 16) & 1u)) >> 16);
}

// async global->LDS, 16B per lane. LDS dest must be wave-uniform base + lane*16.
__device__ __forceinline__ void gl_lds16(const u16* g, u16* l) {
  __builtin_amdgcn_global_load_lds(
      (const __attribute__((address_space(1))) void*)g,
      (__attribute__((address_space(3))) void*)l, 16, 0, 0);
}

// ---------------------------------------------------------------------------
// Transpose role bodies (shared by the fused prep/post kernels).
// dst[c*dst_ld + r] = (bf16)src[r*src_ld + c], 64x64 tile at (c0, r0).
// ---------------------------------------------------------------------------
__device__ __forceinline__ void ktr_f32_body(
    const float* __restrict__ src, u16* __restrict__ dst,
    int src_ld, int dst_ld, int c0, int r0, int tid, u16 (*t)[64]) {
  #pragma unroll
  for (int it = 0; it < 2; ++it) {
    int c = tid + it * 256;
    int r = c >> 3, ch = c & 7;
    const float* sp = src + (long)(r0 + r) * src_ld + c0 + ch * 8;
    float4 v0 = *reinterpret_cast<const float4*>(sp);
    float4 v1 = *reinterpret_cast<const float4*>(sp + 4);
    u16 tmp[8] = {f2bf(v0.x), f2bf(v0.y), f2bf(v0.z), f2bf(v0.w),
                  f2bf(v1.x), f2bf(v1.y), f2bf(v1.z), f2bf(v1.w)};
    int sw = ch ^ (r & 7);
    *reinterpret_cast<uint4*>(&t[r][sw * 8]) = *reinterpret_cast<uint4*>(tmp);
  }
  __syncthreads();
  #pragma unroll
  for (int it = 0; it < 2; ++it) {
    int c = tid + it * 256;
    int rr = c >> 3, ch = c & 7;
    u16 tmp[8];
    #pragma unroll
    for (int j = 0; j < 8; ++j) {
      int k = ch * 8 + j;
      int sw = (rr >> 3) ^ (k & 7);
      tmp[j] = t[k][sw * 8 + (rr & 7)];
    }
    *reinterpret_cast<uint4*>(dst + (long)(c0 + rr) * dst_ld + r0 + ch * 8) =
        *reinterpret_cast<uint4*>(tmp);
  }
}

__device__ __forceinline__ void ktr_bf16_body(
    const u16* __restrict__ s, u16* __restrict__ d,
    int src_ld, int dst_ld, int c0, int r0, int tid, u16 (*t)[64]) {
  #pragma unroll
  for (int it = 0; it < 2; ++it) {
    int c = tid + it * 256;
    int r = c >> 3, ch = c & 7;
    uint4 v = *reinterpret_cast<const uint4*>(s + (long)(r0 + r) * src_ld + c0 + ch * 8);
    int sw = ch ^ (r & 7);
    *reinterpret_cast<uint4*>(&t[r][sw * 8]) = v;
  }
  __syncthreads();
  #pragma unroll
  for (int it = 0; it < 2; ++it) {
    int c = tid + it * 256;
    int rr = c >> 3, ch = c & 7;
    u16 tmp[8];
    #pragma unroll
    for (int j = 0; j < 8; ++j) {
      int k = ch * 8 + j;
      int sw = (rr >> 3) ^ (k & 7);
      tmp[j] = t[k][sw * 8 + (rr & 7)];
    }
    *reinterpret_cast<uint4*>(d + (long)(c0 + rr) * dst_ld + r0 + ch * 8) =
        *reinterpret_cast<uint4*>(tmp);
  }
}

// ---------------------------------------------------------------------------
// Fused PREP kernel: all pre-GEMM1 independent work in ONE launch.
//   role A [0, 9216):      Wqkv (f32 [3072][12288]) -> WqkvT bf16 [12288][3072]
//   role B [9216, 15360):  hidden f32 -> hiddenB bf16 (8 elems/thread)
//   role C [15360, 16384): rope trig table tab[pos*128+i] = cos/sin
// grid: 16384 x 256.
// ---------------------------------------------------------------------------
__global__ __launch_bounds__(256) void prep_kernel(
    const float* __restrict__ hidden, u16* __restrict__ hiddenB,
    const float* __restrict__ Wqkv, u16* __restrict__ WqkvT,
    float2* __restrict__ rtab) {
  __shared__ __align__(16) u16 t[64][64];
  const int bid = blockIdx.x;
  const int tid = threadIdx.x;
  if (bid < 9216) {
    int cx = bid % 192, cy = bid / 192;
    ktr_f32_body(Wqkv, WqkvT, 12288, 3072, cx * 64, cy * 64, tid, t);
  } else if (bid < 15360) {
    long i = (long)((bid - 9216) * 256 + tid) * 8;
    float4 a = *reinterpret_cast<const float4*>(hidden + i);
    float4 b = *reinterpret_cast<const float4*>(hidden + i + 4);
    u16 tmp[8] = {f2bf(a.x), f2bf(a.y), f2bf(a.z), f2bf(a.w),
                  f2bf(b.x), f2bf(b.y), f2bf(b.z), f2bf(b.w)};
    *reinterpret_cast<uint4*>(hiddenB + i) = *reinterpret_cast<uint4*>(tmp);
  } else {
    int idx = (bid - 15360) * 256 + tid;
    int pos = idx >> 7, i = idx & 127;
    float inv_freq = exp2f((float)i * (-13.287712379549449f / 128.0f));
    float ang = (float)pos * inv_freq;
    float sv, cv;
    sincosf(ang, &sv, &cv);
    rtab[idx] = make_float2(cv, sv);
  }
}

// ---------------------------------------------------------------------------
// Fused POST kernel: all post-GEMM1 / pre-attn work in ONE launch.
//   role A [0, 8192):      NeoX rope in-place on qkv q,k cols (table-driven,
//                          8 pairs/thread). Does NOT touch V cols.
//   role B [8192, 12288):  V (qkv cols 8192..12288) -> VT [bh][hd][s]
//   role C [12288, 15360): Wo (f32 [4096? ld=3072]) -> WoT bf16 [3072][4096]
// All reads/writes disjoint (rope: q,k cols; VT: V cols -> VT@159M;
// Wo -> WoT@134M; rtab@201M read-only here). grid: 15360 x 256.
// ---------------------------------------------------------------------------
__global__ __launch_bounds__(256) void post_kernel(
    u16* __restrict__ qkv, const int* __restrict__ positions,
    const float2* __restrict__ tab, u16* __restrict__ VT,
    const float* __restrict__ Wo, u16* __restrict__ WoT) {
  __shared__ __align__(16) u16 t[64][64];
  const int bid = blockIdx.x;
  const int tid = threadIdx.x;
  if (bid < 8192) {
    int idx = bid * 256 + tid;
    int t16 = idx & 15;
    int head = (idx >> 4) & 31;
    int row = idx >> 9;
    int col = (head < NHEADS) ? head * HEADD : 4096 + (head - NHEADS) * HEADD;
    u16* p = qkv + (long)row * QKVW + col + t16 * 8;
    u16 x1[8], x2[8];
    *reinterpret_cast<uint4*>(x1) = *reinterpret_cast<const uint4*>(p);
    *reinterpret_cast<uint4*>(x2) = *reinterpret_cast<const uint4*>(p + 128);
    const float2* e = tab + (long)positions[row] * 128 + t16 * 8;
    u16 o1[8], o2[8];
    #pragma unroll
    for (int j = 0; j < 8; ++j) {
      float c = e[j].x, s = e[j].y;
      float a = bf2f(x1[j]), bb = bf2f(x2[j]);
      o1[j] = f2bf(a * c - bb * s);
      o2[j] = f2bf(bb * c + a * s);
    }
    *reinterpret_cast<uint4*>(p) = *reinterpret_cast<uint4*>(o1);
    *reinterpret_cast<uint4*>(p + 128) = *reinterpret_cast<uint4*>(o2);
  } else if (bid < 12288) {
    int tt = bid - 8192;
    int bx = tt & 3, by = (tt >> 2) & 31, bz = tt >> 7;  // z = b*16 + h
    const u16* s = qkv + 8192 + (long)(bz >> 4) * 25165824L + (long)(bz & 15) * 256L;
    u16* d = VT + (long)(bz >> 4) * 8388608L + (long)(bz & 15) * 524288L;
    ktr_bf16_body(s, d, 12288, 2048, bx * 64, by * 64, tid, t);
  } else {
    int tt = bid - 12288;
    int cx = tt % 48, cy = tt / 48;
    ktr_f32_body(Wo, WoT, 3072, 4096, cx * 64, cy * 64, tid, t);
  }
}

// ---------------------------------------------------------------------------
// C = A @ BT^T : 256x256 tile, BK=64, 8 waves, 8-phase schedule, XOR-swizzled
// LDS.  Proven R1 ledger (306 us / MfmaUtil 44 @ GEMM1):
//   prologue: tile0 full + A0,A1(t1);  ph1(t): A2,A3(t+1); ph2(t): B0,B1(t+1);
//   ph3(t): B2,B3(t+1); ph4(t): A0,A1(t+2) into buf b, vmcnt(2).
// grid: (N/256, M/256)
// ---------------------------------------------------------------------------
template <typename OUT_T>
__global__ __launch_bounds__(512, 2) void gemm_bt8(
    const u16* __restrict__ A, const u16* __restrict__ BT, OUT_T* __restrict__ C,
    int M, int N, int K) {
  (void)M;
  __shared__ __align__(16) u16 As[2][256][64];
  __shared__ __align__(16) u16 Bs[2][256][64];
  const int tid = threadIdx.x;
  const int wave = tid >> 6, lane = tid & 63;
  const int quad = lane >> 4, l16 = lane & 15;
  const int wm = (wave >> 2) * 128, wn = (wave & 3) * 64;
  const long m0 = (long)blockIdx.y * 256, n0 = (long)blockIdx.x * 256;
  const int sw = l16 & 7;
  const int ca0 = (quad ^ sw) * 8;
  const int ca1 = ((4 + quad) ^ sw) * 8;
  const int srow = tid >> 3;
  const int sdst8 = (tid & 7) * 8;
  const int ssrc8 = ((tid & 7) ^ (srow & 7)) * 8;
  const long Kl = K;
  const u16* gA = A + (m0 + srow) * Kl + ssrc8;
  const u16* gB = BT + (n0 + srow) * Kl + ssrc8;
  const int nt = K >> 6;

  f32x4 acc[8][4] = {};
  bf16x8 af[4][2];
  bf16x8 bfr[4][2];

#define STAGE_A(BB, R, K0) \
  gl_lds16(gA + (long)((R) << 6) * Kl + (K0), &As[BB][((R) << 6) + srow][sdst8])
#define STAGE_B(BB, R, K0) \
  gl_lds16(gB + (long)((R) << 6) * Kl + (K0), &Bs[BB][((R) << 6) + srow][sdst8])
#define READ_A(BB, RBASE)                                              \
  _Pragma("unroll") for (int i4 = 0; i4 < 4; ++i4) {                   \
    const u16* p_ = &As[BB][(RBASE) + i4 * 16 + l16][0];               \
    af[i4][0] = *reinterpret_cast<const bf16x8*>(p_ + ca0);            \
    af[i4][1] = *reinterpret_cast<const bf16x8*>(p_ + ca1);            \
  }
#define READ_B(BB, JB)                                                 \
  _Pragma("unroll") for (int j2 = 0; j2 < 2; ++j2) {                   \
    const u16* p_ = &Bs[BB][wn + ((JB) + j2) * 16 + l16][0];           \
    bfr[(JB) + j2][0] = *reinterpret_cast<const bf16x8*>(p_ + ca0);    \
    bfr[(JB) + j2][1] = *reinterpret_cast<const bf16x8*>(p_ + ca1);    \
  }
#define QUADMFMA(MB, NB)                                               \
  _Pragma("unroll") for (int i4 = 0; i4 < 4; ++i4)                     \
  _Pragma("unroll") for (int j2 = 0; j2 < 2; ++j2)                     \
  _Pragma("unroll") for (int s = 0; s < 2; ++s)                        \
    acc[(MB) + i4][(NB) + j2] = __builtin_amdgcn_mfma_f32_16x16x32_bf16( \
        af[i4][s], bfr[(NB) + j2][s], acc[(MB) + i4][(NB) + j2], 0, 0, 0);
#define BAR() asm volatile("s_barrier" ::: "memory")
#define LGKM0() asm volatile("s_waitcnt lgkmcnt(0)" ::: "memory")

  // prologue: tile0 full (8 rounds) -> buf0; tile1 rounds A0,A1 -> buf1
  STAGE_A(0, 0, 0); STAGE_A(0, 1, 0); STAGE_A(0, 2, 0); STAGE_A(0, 3, 0);
  STAGE_B(0, 0, 0); STAGE_B(0, 1, 0); STAGE_B(0, 2, 0); STAGE_B(0, 3, 0);
  if (nt > 1) {
    STAGE_A(1, 0, 64); STAGE_A(1, 1, 64);
    asm volatile("s_waitcnt vmcnt(2)" ::: "memory");
  } else {
    asm volatile("s_waitcnt vmcnt(0)" ::: "memory");
  }
  BAR();

  for (int t = 0; t < nt; ++t) {
    const int b = t & 1;
    const long kn = (long)(t + 1) << 6;
    const long kn2 = (long)(t + 2) << 6;
    const bool st1 = (t + 1 < nt), st2 = (t + 2 < nt);
    // ---- phase 1: reads A(wm)+B0 (12 ds); stage A2,A3(t+1); MFMA Q(0,0)
    READ_A(b, wm);
    READ_B(b, 0);
    if (st1) { STAGE_A(b ^ 1, 2, kn); STAGE_A(b ^ 1, 3, kn); }
    BAR(); LGKM0();
    __builtin_amdgcn_s_setprio(1);
    QUADMFMA(0, 0);
    __builtin_amdgcn_s_setprio(0);
    BAR();
    // ---- phase 2: reads B2 (4 ds); stage B0,B1(t+1); MFMA Q(0,1)
    READ_B(b, 2);
    if (st1) { STAGE_B(b ^ 1, 0, kn); STAGE_B(b ^ 1, 1, kn); }
    BAR(); LGKM0();
    __builtin_amdgcn_s_setprio(1);
    QUADMFMA(0, 2);
    __builtin_amdgcn_s_setprio(0);
    BAR();
    // ---- phase 3: reads A(wm+64) (8 ds); stage B2,B3(t+1); MFMA Q(1,1)
    READ_A(b, wm + 64);
    if (st1) { STAGE_B(b ^ 1, 2, kn); STAGE_B(b ^ 1, 3, kn); }
    BAR(); LGKM0();
    __builtin_amdgcn_s_setprio(1);
    QUADMFMA(4, 2);
    __builtin_amdgcn_s_setprio(0);
    BAR();
    // ---- phase 4: no ds reads; stage A0,A1(t+2) into buf b; MFMA Q(1,0)
    if (st2) { STAGE_A(b, 0, kn2); STAGE_A(b, 1, kn2); }
    BAR();
    __builtin_amdgcn_s_setprio(1);
    QUADMFMA(4, 0);
    __builtin_amdgcn_s_setprio(0);
    if (st2)      asm volatile("s_waitcnt vmcnt(2)" ::: "memory");
    else if (st1) asm volatile("s_waitcnt vmcnt(0)" ::: "memory");
    BAR();
  }

  #pragma unroll
  for (int i = 0; i < 8; ++i)
    #pragma unroll
    for (int j = 0; j < 4; ++j) {
      long col = n0 + wn + j * 16 + l16;
      #pragma unroll
      for (int r = 0; r < 4; ++r) {
        long row = m0 + wm + i * 16 + quad * 4 + r;
        if constexpr (sizeof(OUT_T) == 4)
          C[row * (long)N + col] = acc[i][j][r];
        else
          C[row * (long)N + col] = f2bf(acc[i][j][r]);
      }
    }
#undef STAGE_A
#undef STAGE_B
#undef READ_A
#undef READ_B
#undef QUADMFMA
#undef BAR
#undef LGKM0
}

// ---------------------------------------------------------------------------
// GEMM2 variant: 256(M)x192(N) tiles -> grid 16x16 = 256 blocks = 1 block/CU,
// exactly 1 round (256x256 tiling left 64 CUs idle). 8 waves as 4M x 2N:
// per wave 64x96, acc[4][6], 12 MFMA/phase. 7 staging rounds (4A+3B),
// R1-style ledger; vmcnt(2) drains exactly t+1's 7 rounds. LDS 112 KB.
// grid: (N/192, M/256)
// ---------------------------------------------------------------------------
__global__ __launch_bounds__(512, 1) void gemm_bt8_n192(
    const u16* __restrict__ A, const u16* __restrict__ BT, float* __restrict__ C,
    int M, int N, int K) {
  (void)M;
  __shared__ __align__(16) u16 As[2][256][64];
  __shared__ __align__(16) u16 Bs[2][192][64];
  const int tid = threadIdx.x;
  const int wave = tid >> 6, lane = tid & 63;
  const int quad = lane >> 4, l16 = lane & 15;
  const int wm = (wave >> 1) * 64, wn = (wave & 1) * 96;
  const long m0 = (long)blockIdx.y * 256, n0 = (long)blockIdx.x * 192;
  const int sw = l16 & 7;
  const int ca0 = (quad ^ sw) * 8;
  const int ca1 = ((4 + quad) ^ sw) * 8;
  const int srow = tid >> 3;
  const int sdst8 = (tid & 7) * 8;
  const int ssrc8 = ((tid & 7) ^ (srow & 7)) * 8;
  const long Kl = K;
  const u16* gA = A + (m0 + srow) * Kl + ssrc8;
  const u16* gB = BT + (n0 + srow) * Kl + ssrc8;
  const int nt = K >> 6;

  f32x4 acc[4][6] = {};
  bf16x8 af[2][2];
  bf16x8 bfr[6][2];

#define STAGE_A(BB, R, K0) \
  gl_lds16(gA + (long)((R) << 6) * Kl + (K0), &As[BB][((R) << 6) + srow][sdst8])
#define STAGE_B(BB, R, K0) \
  gl_lds16(gB + (long)((R) << 6) * Kl + (K0), &Bs[BB][((R) << 6) + srow][sdst8])
#define READ_A2(BB, RBASE)                                             \
  _Pragma("unroll") for (int i4 = 0; i4 < 2; ++i4) {                   \
    const u16* p_ = &As[BB][(RBASE) + i4 * 16 + l16][0];               \
    af[i4][0] = *reinterpret_cast<const bf16x8*>(p_ + ca0);            \
    af[i4][1] = *reinterpret_cast<const bf16x8*>(p_ + ca1);            \
  }
#define READ_B3(BB, JB)                                                \
  _Pragma("unroll") for (int j3 = 0; j3 < 3; ++j3) {                   \
    const u16* p_ = &Bs[BB][wn + ((JB) + j3) * 16 + l16][0];           \
    bfr[(JB) + j3][0] = *reinterpret_cast<const bf16x8*>(p_ + ca0);    \
    bfr[(JB) + j3][1] = *reinterpret_cast<const bf16x8*>(p_ + ca1);    \
  }
#define QMFMA(IB, JB)                                                  \
  _Pragma("unroll") for (int i4 = 0; i4 < 2; ++i4)                     \
  _Pragma("unroll") for (int j3 = 0; j3 < 3; ++j3)                     \
  _Pragma("unroll") for (int s = 0; s < 2; ++s)                        \
    acc[(IB) + i4][(JB) + j3] = __builtin_amdgcn_mfma_f32_16x16x32_bf16( \
        af[i4][s], bfr[(JB) + j3][s], acc[(IB) + i4][(JB) + j3], 0, 0, 0);
#define BAR() asm volatile("s_barrier" ::: "memory")
#define LGKM0() asm volatile("s_waitcnt lgkmcnt(0)" ::: "memory")

  STAGE_A(0, 0, 0); STAGE_A(0, 1, 0); STAGE_A(0, 2, 0); STAGE_A(0, 3, 0);
  STAGE_B(0, 0, 0); STAGE_B(0, 1, 0); STAGE_B(0, 2, 0);
  if (nt > 1) {
    STAGE_A(1, 0, 64); STAGE_A(1, 1, 64);
    asm volatile("s_waitcnt vmcnt(2)" ::: "memory");
  } else {
    asm volatile("s_waitcnt vmcnt(0)" ::: "memory");
  }
  BAR();

  for (int t = 0; t < nt; ++t) {
    const int b = t & 1;
    const long kn = (long)(t + 1) << 6;
    const long kn2 = (long)(t + 2) << 6;
    const bool st1 = (t + 1 < nt), st2 = (t + 2 < nt);
    READ_A2(b, wm);
    READ_B3(b, 0);
    if (st1) { STAGE_A(b ^ 1, 2, kn); STAGE_A(b ^ 1, 3, kn); }
    BAR(); LGKM0();
    __builtin_amdgcn_s_setprio(1);
    QMFMA(0, 0);
    __builtin_amdgcn_s_setprio(0);
    BAR();
    READ_B3(b, 3);
    if (st1) { STAGE_B(b ^ 1, 0, kn); STAGE_B(b ^ 1, 1, kn); }
    BAR(); LGKM0();
    __builtin_amdgcn_s_setprio(1);
    QMFMA(0, 3);
    __builtin_amdgcn_s_setprio(0);
    BAR();
    READ_A2(b, wm + 32);
    if (st1) { STAGE_B(b ^ 1, 2, kn); }
    BAR(); LGKM0();
    __builtin_amdgcn_s_setprio(1);
    QMFMA(2, 3);
    __builtin_amdgcn_s_setprio(0);
    BAR();
    if (st2) { STAGE_A(b, 0, kn2); STAGE_A(b, 1, kn2); }
    BAR();
    __builtin_amdgcn_s_setprio(1);
    QMFMA(2, 0);
    __builtin_amdgcn_s_setprio(0);
    if (st2)      asm volatile("s_waitcnt vmcnt(2)" ::: "memory");
    else if (st1) asm volatile("s_waitcnt vmcnt(0)" ::: "memory");
    BAR();
  }

  #pragma unroll
  for (int i = 0; i < 4; ++i)
    #pragma unroll
    for (int j = 0; j < 6; ++j) {
      long col = n0 + wn + j * 16 + l16;
      #pragma unroll
      for (int r = 0; r < 4; ++r) {
        long row = m0 + wm + i * 16 + quad * 4 + r;
        C[row * (long)N + col] = acc[i][j][r];
      }
    }
#undef STAGE_A
#undef STAGE_B
#undef READ_A2
#undef READ_B3
#undef QMFMA
#undef BAR
#undef LGKM0
}

// ---------------------------------------------------------------------------
// Flash attention, causal, load-balanced persistent blocks.
// SINGLE-buffered K/V (73 KB LDS -> 2 blocks/CU), software-pipelined staging:
//   invariant at loop top: K(kt) visible, V(kt) 8 loads in flight.
//   QK^T; BAR; issue K(kt+1) [covered by softmax+PV]; softmax; vmcnt(8)
//   drains V(kt); BAR; P relayout; PV; BAR; issue V(kt+1); vmcnt(8) drains
//   K(kt+1); BAR.  grid: (16, B*NH), 256 threads, 2 blocks/CU.
// ---------------------------------------------------------------------------
__global__ __launch_bounds__(256, 2) void attn_kernel(
    const u16* __restrict__ qkv, const u16* __restrict__ VT,
    u16* __restrict__ attnout) {
  const int p = blockIdx.x;
  const int bh = blockIdx.y;
  const int b = bh >> 4, h = bh & 15;
  const int tid = threadIdx.x;
  const int wave = tid >> 6, lane = tid & 63;
  const int quad = lane >> 4, l16 = lane & 15;
  const int sw7 = l16 & 7;

  __shared__ __align__(16) u16 Ks[64][256];  // K tile, XOR-swizzled
  __shared__ __align__(16) u16 Vs[256][64];  // V^T tile, XOR-swizzled
  __shared__ __align__(16) u16 Ps[64][72];   // P relayout (wave-private rows)

  const u16* qp = qkv + (long)b * SQLEN * QKVW + h * HEADD;
  const u16* kp = qp + 4096;
  const u16* vtp = VT + (long)bh * HEADD * SQLEN;
  const float cs = 0.0625f * 1.4426950408889634f;  // scale * log2(e)

  const u16* ksrc = kp + (long)(tid >> 5) * QKVW + ((tid & 31) ^ ((tid >> 5) & 7)) * 8;
  const u16* vsrc = vtp + (long)(tid >> 3) * SQLEN + ((tid & 7) ^ ((tid >> 3) & 7)) * 8;
  u16* kdst = &Ks[0][0] + tid * 8;
  u16* vdst = &Vs[0][0] + tid * 8;

#define STAGE_K(KT) { const u16* gk_ = ksrc + (long)(KT) * 64 * QKVW;          \
  _Pragma("unroll") for (int it = 0; it < 8; ++it)                             \
    gl_lds16(gk_ + (long)it * 8 * QKVW, kdst + it * 2048); }
#define STAGE_V(KT) { const u16* gv_ = vsrc + (KT) * 64;                       \
  _Pragma("unroll") for (int it = 0; it < 8; ++it)                             \
    gl_lds16(gv_ + (long)it * 32 * SQLEN, vdst + it * 2048); }
#define ABAR() asm volatile("s_barrier" ::: "memory")
#define VM8()  asm volatile("s_waitcnt vmcnt(8)" ::: "memory")
#define VM0()  asm volatile("s_waitcnt vmcnt(0)" ::: "memory")

  for (int half = 0; half < 2; ++half) {
    const int qt = half ? p : 31 - p;  // heavy tile first

    ABAR();  // prev half's LDS readers done before restaging
    const u16* qrow = qp + (long)(qt * 64 + wave * 16 + l16) * QKVW + quad * 8;
    bf16x8 qf[8];
    #pragma unroll
    for (int s = 0; s < 8; ++s)
      qf[s] = *reinterpret_cast<const bf16x8*>(qrow + s * 32);

    STAGE_K(0); STAGE_V(0);
    VM8();   // K landed (drains qf loads + K; leaves V's 8 in flight)
    ABAR();  // K visible to all waves

    float m_i[4], l_i[4];
    #pragma unroll
    for (int r = 0; r < 4; ++r) { m_i[r] = -INFINITY; l_i[r] = 0.f; }
    f32x4 o[16] = {};

    for (int kt = 0; kt <= qt; ++kt) {
      const bool more = (kt < qt);
      // ---- QK^T (reads Ks)
      f32x4 sc[4] = {};
      __builtin_amdgcn_s_setprio(1);
      #pragma unroll
      for (int s = 0; s < 8; ++s) {
        #pragma unroll
        for (int nb = 0; nb < 4; ++nb) {
          bf16x8 kf = *reinterpret_cast<const bf16x8*>(
              &Ks[nb * 16 + l16][(((s << 2) + quad) ^ sw7) * 8]);
          sc[nb] = __builtin_amdgcn_mfma_f32_16x16x32_bf16(qf[s], kf, sc[nb], 0, 0, 0);
        }
      }
      __builtin_amdgcn_s_setprio(0);
      ABAR();                       // all waves done reading Ks
      if (more) STAGE_K(kt + 1);    // overwrite Ks; covered by softmax+PV
      // ---- mask + online softmax (always rescale)
      const bool diag = (kt == qt);
      #pragma unroll
      for (int nb = 0; nb < 4; ++nb)
        #pragma unroll
        for (int r = 0; r < 4; ++r) {
          float v = sc[nb][r] * cs;
          if (diag) {
            int colL = nb * 16 + l16, rowL = wave * 16 + quad * 4 + r;
            if (colL > rowL) v = -INFINITY;
          }
          sc[nb][r] = v;
        }
      float alpha[4];
      #pragma unroll
      for (int r = 0; r < 4; ++r) {
        float t = fmaxf(fmaxf(sc[0][r], sc[1][r]), fmaxf(sc[2][r], sc[3][r]));
        #pragma unroll
        for (int d = 1; d < 16; d <<= 1) t = fmaxf(t, __shfl_xor(t, d));
        float mn = fmaxf(m_i[r], t);
        alpha[r] = exp2f(m_i[r] - mn);
        m_i[r] = mn;
      }
      #pragma unroll
      for (int r = 0; r < 4; ++r) {
        float t = 0.f;
        #pragma unroll
        for (int nb = 0; nb < 4; ++nb) {
          float pr = exp2f(sc[nb][r] - m_i[r]);
          sc[nb][r] = pr;
          t += pr;
        }
        #pragma unroll
        for (int d = 1; d < 16; d <<= 1) t += __shfl_xor(t, d);
        l_i[r] = l_i[r] * alpha[r] + t;
      }
      // ---- V(kt) drain: vmcnt(8) leaves K(kt+1)'s 8 in flight (tail: 0)
      if (more) VM8(); else VM0();
      ABAR();                       // V visible to all waves
      // ---- P relayout (wave-private rows) + O rescale
      #pragma unroll
      for (int nb = 0; nb < 4; ++nb)
        #pragma unroll
        for (int r = 0; r < 4; ++r)
          Ps[wave * 16 + quad * 4 + r][nb * 16 + l16] = f2bf(sc[nb][r]);
      #pragma unroll
      for (int c16 = 0; c16 < 16; ++c16)
        #pragma unroll
        for (int r = 0; r < 4; ++r)
          o[c16][r] *= alpha[r];
      bf16x8 pf[2];
      #pragma unroll
      for (int s2 = 0; s2 < 2; ++s2)
        pf[s2] = *reinterpret_cast<const bf16x8*>(&Ps[wave * 16 + l16][s2 * 32 + quad * 8]);
      // ---- PV (reads Vs)
      __builtin_amdgcn_s_setprio(1);
      #pragma unroll
      for (int c16 = 0; c16 < 16; ++c16) {
        #pragma unroll
        for (int s2 = 0; s2 < 2; ++s2) {
          bf16x8 vf = *reinterpret_cast<const bf16x8*>(
              &Vs[c16 * 16 + l16][(((s2 << 2) + quad) ^ sw7) * 8]);
          o[c16] = __builtin_amdgcn_mfma_f32_16x16x32_bf16(pf[s2], vf, o[c16], 0, 0, 0);
        }
      }
      __builtin_amdgcn_s_setprio(0);
      if (more) {
        ABAR();                     // all waves done reading Vs
        STAGE_V(kt + 1);            // covered by next QK^T+softmax
        VM8();                      // K(kt+1) landed; V(kt+1) in flight
        ABAR();                     // K visible
      }
    }
    // ---- epilogue
    #pragma unroll
    for (int r = 0; r < 4; ++r) {
      float inv = 1.0f / l_i[r];
      long q = qt * 64 + wave * 16 + quad * 4 + r;
      long rowoff = ((long)b * SQLEN + q) * 4096 + h * HEADD;
      #pragma unroll
      for (int c16 = 0; c16 < 16; ++c16)
        attnout[rowoff + c16 * 16 + l16] = f2bf(o[c16][r] * inv);
    }
  }
#undef STAGE_K
#undef STAGE_V
#undef ABAR
#undef VM8
#undef VM0
}

// ---------------------------------------------------------------------------
extern "C" void kernel_launch(void* const* d_in, const int* in_sizes, int n_in,
                              void* d_out, int out_size, void* d_ws, size_t ws_size,
                              hipStream_t stream) {
  const float* hidden = (const float*)d_in[0];
  const int* positions = (const int*)d_in[1];
  const float* Wqkv = (const float*)d_in[2];
  const float* Wo = (const float*)d_in[3];
  float* out = (float*)d_out;
  char* ws = (char*)d_ws;

  // workspace layout (bytes), total 200 MiB. Lifetimes:
  //   [0, 100663296)           qkv   4096x12288 bf16        GEMM1 -> attn
  //   [100663296, 176160768)   WqkvT 12288x3072 bf16        prep -> GEMM1
  //   after GEMM1 (WqkvT dead), same region re-used:
  //     [100663296, 134217728)   attn 4096x4096 bf16        attn -> GEMM2
  //     [134217728, 159383552)   WoT  3072x4096 bf16        post -> GEMM2
  //     [159383552, 193137984)   VT 32x256x2048 bf16        post -> attn
  //                              (also overlaps dead hiddenB tail)
  //   [176160768, 201326592)   hiddenB 4096x3072 bf16       prep -> GEMM1
  //   [201326592, 203423744)   rope cos/sin table f32x2     prep -> post
  //                              (no writer after prep; VT now ends 193M)
  u16* qkv     = (u16*)(ws);
  u16* WqkvT   = (u16*)(ws + 100663296L);
  u16* attn    = (u16*)(ws + 100663296L);
  u16* WoT     = (u16*)(ws + 134217728L);
  u16* VT      = (u16*)(ws + 159383552L);
  u16* hiddenB = (u16*)(ws + 176160768L);
  float2* rtab = (float2*)(ws + 201326592L);

  prep_kernel<<<dim3(16384, 1, 1), 256, 0, stream>>>(
      hidden, hiddenB, Wqkv, WqkvT, rtab);
  gemm_bt8<u16><<<dim3(48, 16, 1), 512, 0, stream>>>(
      hiddenB, WqkvT, qkv, 4096, 12288, 3072);
  post_kernel<<<dim3(15360, 1, 1), 256, 0, stream>>>(
      qkv, positions, rtab, VT, Wo, WoT);
  attn_kernel<<<dim3(16, 32, 1), 256, 0, stream>>>(qkv, VT, attn);
  gemm_bt8_n192<<<dim3(16, 16, 1), 512, 0, stream>>>(
      attn, WoT, out, 4096, 3072, 4096);
}